// Round 1
// baseline (4312.004 us; speedup 1.0000x reference)
//
#include <hip/hip_runtime.h>
#include <stdint.h>

#define NEGV (-1e30f)

constexpr int B_  = 32;
constexpr int L1_ = 512;
constexpr int H_  = 128;
constexpr int M_  = 64;     // LQ + LA
constexpr int NK_ = B_ * M_; // 2048

// ---------------------------------------------------------------------------
// K0: detect mask storage dtype (bool/uint8 vs int32 vs float32) and build
// a normalized pad[2048] byte array in ws. True = masked.
// ---------------------------------------------------------------------------
__global__ void prep_pad_kernel(const uint8_t* __restrict__ qm,
                                const uint8_t* __restrict__ am,
                                uint8_t* __restrict__ pad) {
    __shared__ int mode; // 0=int32, 1=float32, 2=byte
    if (threadIdx.x == 0) {
        int nz_mod0 = 0, nz_rest = 0;
        for (int i = 0; i < 1024; ++i) { // 1024 B is safe under all layouts
            int v = (int)qm[i] | (int)am[i];
            if ((i & 3) == 0) nz_mod0 |= v; else nz_rest |= v;
        }
        int m;
        if (nz_mod0 && !nz_rest)      m = 0; // int32 0/1 little-endian
        else if (!nz_mod0 && nz_rest) m = 1; // float32 0.0/1.0
        else                          m = 2; // raw bytes (numpy bool)
        mode = m;
    }
    __syncthreads();
    int md = mode;
    for (int k = threadIdx.x; k < NK_; k += blockDim.x) {
        int b2 = k >> 6, r = k & 63;
        int idx = b2 * 32 + (r < 32 ? r : r - 32);
        const uint8_t* src = (r < 32) ? qm : am;
        int v;
        if (md == 0)      v = (((const int*)src)[idx] != 0);
        else if (md == 1) v = (((const float*)src)[idx] != 0.0f);
        else              v = (src[idx] != 0);
        pad[k] = (uint8_t)v;
    }
}

// ---------------------------------------------------------------------------
// K1: materialize dlg (2048x128) and y_proj = relu(dlg @ W.T + b) into ws.
// One block (128 threads) per dialog token row.
// ---------------------------------------------------------------------------
__global__ void yproj_kernel(const float* __restrict__ xq,
                             const float* __restrict__ xa,
                             const float* __restrict__ W,
                             const float* __restrict__ bias,
                             float* __restrict__ dlg,
                             float* __restrict__ yproj) {
    int k = blockIdx.x;
    int b2 = k >> 6, r = k & 63;
    const float* src = (r < 32) ? (xq + (size_t)(b2 * 32 + r) * H_)
                                : (xa + (size_t)(b2 * 32 + (r - 32)) * H_);
    __shared__ __align__(16) float row[H_];
    int c = threadIdx.x;
    float v = src[c];
    row[c] = v;
    dlg[(size_t)k * H_ + c] = v;
    __syncthreads();
    float acc = bias[c];
    const float4* w4 = (const float4*)(W + (size_t)c * H_);
    const float4* x4 = (const float4*)row;
#pragma unroll
    for (int d4 = 0; d4 < H_ / 4; ++d4) {
        float4 w = w4[d4], x = x4[d4];
        acc += w.x * x.x + w.y * x.y + w.z * x.z + w.w * x.w;
    }
    yproj[(size_t)k * H_ + c] = fmaxf(acc, 0.0f);
}

// ---------------------------------------------------------------------------
// K2: per (t,l) row — fused x-projection, masked/biased scores over k<64t,
// softmax, PV. 256 threads / block.
// ---------------------------------------------------------------------------
__launch_bounds__(256)
__global__ void attn_kernel(const float* __restrict__ xd,
                            const float* __restrict__ W,
                            const float* __restrict__ bias,
                            const float* __restrict__ rw,
                            const uint8_t* __restrict__ pad,
                            const float* __restrict__ dlg,
                            const float* __restrict__ yproj,
                            float* __restrict__ out) {
    int bid = blockIdx.x;
    int t = bid >> 9;        // batch index == timestep
    int l = bid & 511;
    int tid = threadIdx.x;
    float* orow = out + (size_t)(t * L1_ + l) * H_;

    if (t == 0) {            // zero_first: batch-0 output is exactly 0
        if (tid < H_) orow[tid] = 0.0f;
        return;
    }

    __shared__ __align__(16) float xrow[H_];
    __shared__ __align__(16) float xp[H_];
    __shared__ float s[1984];   // max nk = 64*31
    __shared__ float red[8];
    __shared__ float red2[H_];

    const float* xsrc = xd + (size_t)(t * L1_ + l) * H_;
    if (tid < H_) xrow[tid] = xsrc[tid];
    __syncthreads();

    // fused x projection: xp = relu(xrow @ W.T + b)
    if (tid < H_) {
        float acc = bias[tid];
        const float4* w4 = (const float4*)(W + (size_t)tid * H_);
        const float4* x4 = (const float4*)xrow;
#pragma unroll
        for (int d4 = 0; d4 < H_ / 4; ++d4) {
            float4 w = w4[d4], x = x4[d4];
            acc += w.x * x.x + w.y * x.y + w.z * x.z + w.w * x.w;
        }
        xp[tid] = fmaxf(acc, 0.0f);
    }
    __syncthreads();

    const int nk = t << 6;   // only k < 64t can be unmasked
    const float rww = rw[0];

    // scores
    for (int k = tid; k < nk; k += 256) {
        float acc = 0.0f;
        const float4* y4 = (const float4*)(yproj + (size_t)k * H_);
        const float4* x4 = (const float4*)xp;
#pragma unroll
        for (int d4 = 0; d4 < H_ / 4; ++d4) {
            float4 w = y4[d4], x = x4[d4];
            acc += w.x * x.x + w.y * x.y + w.z * x.z + w.w * x.w;
        }
        int jts = k >> 6;
        float sv = pad[k] ? NEGV : acc;
        s[k] = sv + rww * (float)(t - jts);
    }
    __syncthreads();

    // softmax: block max
    float lm = -INFINITY;
    for (int k = tid; k < nk; k += 256) lm = fmaxf(lm, s[k]);
#pragma unroll
    for (int off = 32; off; off >>= 1) lm = fmaxf(lm, __shfl_down(lm, off, 64));
    int wave = tid >> 6;
    if ((tid & 63) == 0) red[wave] = lm;
    __syncthreads();
    if (tid == 0) {
        float m2 = red[0];
        for (int w = 1; w < 4; ++w) m2 = fmaxf(m2, red[w]);
        red[0] = m2;
    }
    __syncthreads();
    float mx = red[0];

    // exp + sum
    float lsum = 0.0f;
    for (int k = tid; k < nk; k += 256) {
        float e = expf(s[k] - mx);
        s[k] = e;
        lsum += e;
    }
#pragma unroll
    for (int off = 32; off; off >>= 1) lsum += __shfl_down(lsum, off, 64);
    if ((tid & 63) == 0) red[4 + wave] = lsum;
    __syncthreads();
    if (tid == 0) red[4] = 1.0f / (red[4] + red[5] + red[6] + red[7]);
    __syncthreads();
    float inv = red[4];

    // PV: out[c] = inv * sum_k s[k] * dlg[k][c], 2-way k split
    int g = tid >> 7;
    int c = tid & 127;
    float acc = 0.0f;
    for (int k = g; k < nk; k += 2) acc += s[k] * dlg[(size_t)k * H_ + c];
    if (g == 0) red2[c] = acc;
    __syncthreads();
    if (g == 1) orow[c] = (red2[c] + acc) * inv;
}

// ---------------------------------------------------------------------------
extern "C" void kernel_launch(void* const* d_in, const int* in_sizes, int n_in,
                              void* d_out, int out_size, void* d_ws, size_t ws_size,
                              hipStream_t stream) {
    const float*   xd   = (const float*)d_in[0];
    const float*   xq   = (const float*)d_in[1];
    const float*   xa   = (const float*)d_in[2];
    const float*   W    = (const float*)d_in[3];
    const float*   bias = (const float*)d_in[4];
    const float*   rw   = (const float*)d_in[5];
    const uint8_t* qm   = (const uint8_t*)d_in[6];
    const uint8_t* am   = (const uint8_t*)d_in[7];
    float* out = (float*)d_out;

    uint8_t* ws    = (uint8_t*)d_ws;
    uint8_t* pad   = ws;                                  // 2048 B
    float*   dlg   = (float*)(ws + 4096);                 // 1 MB
    float*   yproj = (float*)(ws + 4096 + (size_t)NK_ * H_ * 4); // 1 MB

    hipLaunchKernelGGL(prep_pad_kernel, dim3(1), dim3(256), 0, stream, qm, am, pad);
    hipLaunchKernelGGL(yproj_kernel, dim3(NK_), dim3(128), 0, stream,
                       xq, xa, W, bias, dlg, yproj);
    hipLaunchKernelGGL(attn_kernel, dim3(B_ * L1_), dim3(256), 0, stream,
                       xd, W, bias, rw, pad, dlg, yproj, out);
}

// Round 3
// 114.938 us; speedup vs baseline: 37.5161x; 37.5161x over previous
//
#include <hip/hip_runtime.h>
#include <stdint.h>

#define NEGV (-1e30f)

constexpr int B_  = 32;
constexpr int L1_ = 512;
constexpr int H_  = 128;
constexpr int NK_ = 2048;   // B_ * 64

typedef __attribute__((ext_vector_type(8))) _Float16 f16x8;
typedef __attribute__((ext_vector_type(4))) float    f32x4;

static __device__ __forceinline__ uint16_t f2h(float x) {
    _Float16 h = (_Float16)x;
    union { _Float16 h; uint16_t u; } cv; cv.h = h;
    return cv.u;
}

// ---------------------------------------------------------------------------
// K0: detect mask dtype, build pad[2048] bytes (1 = masked)
// ---------------------------------------------------------------------------
__global__ void prep_pad_kernel(const uint8_t* __restrict__ qm,
                                const uint8_t* __restrict__ am,
                                uint8_t* __restrict__ pad) {
    __shared__ int mode;
    if (threadIdx.x == 0) {
        int nz_mod0 = 0, nz_rest = 0;
        for (int i = 0; i < 1024; ++i) {
            int v = (int)qm[i] | (int)am[i];
            if ((i & 3) == 0) nz_mod0 |= v; else nz_rest |= v;
        }
        int m;
        if (nz_mod0 && !nz_rest)      m = 0;  // int32
        else if (!nz_mod0 && nz_rest) m = 1;  // float32
        else                          m = 2;  // bytes
        mode = m;
    }
    __syncthreads();
    int md = mode;
    for (int k = threadIdx.x; k < NK_; k += blockDim.x) {
        int b2 = k >> 6, r = k & 63;
        int idx = b2 * 32 + (r < 32 ? r : r - 32);
        const uint8_t* src = (r < 32) ? qm : am;
        int v;
        if (md == 0)      v = (((const int*)src)[idx] != 0);
        else if (md == 1) v = (((const float*)src)[idx] != 0.0f);
        else              v = (src[idx] != 0);
        pad[k] = (uint8_t)v;
    }
}

// ---------------------------------------------------------------------------
// K1: y_proj = relu(dlg @ W.T + b) in f32, stored fp16 [2048][128]
// ---------------------------------------------------------------------------
__global__ void yproj_kernel(const float* __restrict__ xq,
                             const float* __restrict__ xa,
                             const float* __restrict__ W,
                             const float* __restrict__ bias,
                             uint16_t* __restrict__ y_h) {
    int k = blockIdx.x;
    int b2 = k >> 6, r = k & 63;
    const float* src = (r < 32) ? (xq + (size_t)(b2 * 32 + r) * H_)
                                : (xa + (size_t)(b2 * 32 + (r - 32)) * H_);
    __shared__ __align__(16) float row[H_];
    int c = threadIdx.x;
    row[c] = src[c];
    __syncthreads();
    float acc = bias[c];
    const f32x4* w4 = (const f32x4*)(W + (size_t)c * H_);
    const f32x4* x4 = (const f32x4*)row;
#pragma unroll
    for (int d4 = 0; d4 < H_ / 4; ++d4) {
        f32x4 w = w4[d4], x = x4[d4];
        acc += w[0]*x[0] + w[1]*x[1] + w[2]*x[2] + w[3]*x[3];
    }
    y_h[(size_t)k * H_ + c] = f2h(fmaxf(acc, 0.0f));
}

// ---------------------------------------------------------------------------
// K2: dlgT [128][2048] = transpose of dialog (original values, fp16)
// one block per turn (64 k-rows)
// ---------------------------------------------------------------------------
__global__ void dlgT_kernel(const float* __restrict__ xq,
                            const float* __restrict__ xa,
                            uint16_t* __restrict__ dlgT) {
    int b2 = blockIdx.x;           // 0..31
    __shared__ __align__(16) float ld[64 * 128];
    int tid = threadIdx.x;         // 256
    f32x4* ld4 = (f32x4*)ld;
#pragma unroll
    for (int i = 0; i < 8; ++i) {
        int idx = tid + i * 256;   // 2048 float4s
        int row = idx >> 5, d4 = idx & 31;
        const float* src = (row < 32) ? (xq + (size_t)(b2 * 32 + row) * H_)
                                      : (xa + (size_t)(b2 * 32 + row - 32) * H_);
        ld4[idx] = *(const f32x4*)(src + d4 * 4);
    }
    __syncthreads();
    int c = tid & 127, half = tid >> 7;   // half selects k 0-31 / 32-63
    uint32_t u[16];
#pragma unroll
    for (int j = 0; j < 16; ++j) {
        float v0 = ld[(half * 32 + 2 * j) * 128 + c];
        float v1 = ld[(half * 32 + 2 * j + 1) * 128 + c];
        u[j] = (uint32_t)f2h(v0) | ((uint32_t)f2h(v1) << 16);
    }
    uint32_t* dst = (uint32_t*)(dlgT + (size_t)c * NK_ + b2 * 64 + half * 32);
#pragma unroll
    for (int j = 0; j < 16; ++j) dst[j] = u[j];
}

// ---------------------------------------------------------------------------
// K3: x_proj = relu(xd @ W.T + b) in f32, stored fp16 [16384][128]
// block = 16 rows, 256 threads
// ---------------------------------------------------------------------------
__global__ __launch_bounds__(256) void xproj_kernel(const float* __restrict__ xd,
                                                    const float* __restrict__ W,
                                                    const float* __restrict__ bias,
                                                    uint16_t* __restrict__ xp_h) {
    int blk = blockIdx.x;          // 1024 blocks
    int tid = threadIdx.x;
    __shared__ __align__(16) float xr[16 * 128];
    f32x4* xr4 = (f32x4*)xr;
#pragma unroll
    for (int i = 0; i < 2; ++i) {
        int idx = tid + i * 256;   // 512 float4s
        xr4[idx] = *(const f32x4*)(xd + (size_t)blk * 16 * H_ + idx * 4);
    }
    __syncthreads();
    int c = tid & 127, rh = tid >> 7;
    float acc[8];
#pragma unroll
    for (int i = 0; i < 8; ++i) acc[i] = 0.0f;
    const f32x4* w4 = (const f32x4*)(W + (size_t)c * H_);
    for (int d4 = 0; d4 < 32; ++d4) {
        f32x4 w = w4[d4];
#pragma unroll
        for (int i = 0; i < 8; ++i) {
            f32x4 x = xr4[(rh * 8 + i) * 32 + d4];
            acc[i] += w[0]*x[0] + w[1]*x[1] + w[2]*x[2] + w[3]*x[3];
        }
    }
    float bc = bias[c];
#pragma unroll
    for (int i = 0; i < 8; ++i)
        xp_h[(size_t)(blk * 16 + rh * 8 + i) * H_ + c] = f2h(fmaxf(acc[i] + bc, 0.0f));
}

// ---------------------------------------------------------------------------
// K4: flash attention, fp16 MFMA.  Block = (t, 32 l-rows), 4 waves.
// S^T = y_proj . x_proj^T  (so P rows land on lane&15 for PV A-frags)
// ---------------------------------------------------------------------------
__global__ __launch_bounds__(256, 2) void attn_kernel(
        const uint16_t* __restrict__ xp_h,
        const uint16_t* __restrict__ y_h,
        const uint16_t* __restrict__ dlgT,
        const uint8_t*  __restrict__ pad,
        const float*    __restrict__ rw,
        float* __restrict__ out) {
    int bid = blockIdx.x;
    int t  = (bid < 256) ? (31 - (bid >> 4)) : ((bid - 256) >> 4);  // pair t with 31-t per CU
    int lt = bid & 15;
    int l0 = lt * 32;
    int tid = threadIdx.x;

    if (t == 0) {                  // zero_first
        f32x4 z = {0.f, 0.f, 0.f, 0.f};
        f32x4* o4 = (f32x4*)(out + (size_t)l0 * H_);
        for (int i = tid; i < 32 * 32; i += 256) o4[i] = z;
        return;
    }

    int w = tid >> 6, lane = tid & 63, n16 = lane & 15, g = lane >> 4;

    __shared__ __align__(16) uint16_t P_lds[32 * 64];   // fp16, XOR-swizzled rows
    __shared__ __align__(16) float pmax[32 * 4];
    __shared__ __align__(16) float psum[32 * 4];
    __shared__ float m_lds[32], l_lds[32], sc_lds[32];

    // x_proj B-fragments, held in registers for the whole kernel
    f16x8 xf[2][4];
#pragma unroll
    for (int rT = 0; rT < 2; ++rT)
#pragma unroll
        for (int ks = 0; ks < 4; ++ks) {
            size_t R = (size_t)(t * L1_ + l0 + rT * 16 + n16);
            xf[rT][ks] = *(const f16x8*)(xp_h + R * H_ + ks * 32 + g * 8);
        }

    f32x4 zero4 = {0.f, 0.f, 0.f, 0.f};
    f32x4 acc[2][2];
#pragma unroll
    for (int a = 0; a < 2; ++a)
#pragma unroll
        for (int b = 0; b < 2; ++b) acc[a][b] = zero4;

    if (tid < 32) { m_lds[tid] = -INFINITY; l_lds[tid] = 0.0f; }
    float rww = rw[0];
    __syncthreads();

    for (int kt = 0; kt < t; ++kt) {
        // ---- load fragments for this k-tile
        f16x8 yf[4];
        size_t kkb = (size_t)(kt * 64 + w * 16 + n16);
#pragma unroll
        for (int ks = 0; ks < 4; ++ks)
            yf[ks] = *(const f16x8*)(y_h + kkb * H_ + ks * 32 + g * 8);
        f16x8 vb[2][2];
#pragma unroll
        for (int cT = 0; cT < 2; ++cT)
#pragma unroll
            for (int ks = 0; ks < 2; ++ks) {
                size_t c = (size_t)(w * 32 + cT * 16 + n16);
                vb[cT][ks] = *(const f16x8*)(dlgT + c * NK_ + kt * 64 + ks * 32 + g * 8);
            }
        uint32_t padw = *(const uint32_t*)(pad + kt * 64 + w * 16 + g * 4);

        // ---- S^T MFMAs: D[kk][r], kk-tile = w
        f32x4 ss[2];
        ss[0] = zero4; ss[1] = zero4;
#pragma unroll
        for (int ks = 0; ks < 4; ++ks) {
            ss[0] = __builtin_amdgcn_mfma_f32_16x16x32_f16(yf[ks], xf[0][ks], ss[0], 0, 0, 0);
            ss[1] = __builtin_amdgcn_mfma_f32_16x16x32_f16(yf[ks], xf[1][ks], ss[1], 0, 0, 0);
        }

        // ---- bias + pad mask; lane holds kk = w*16+g*4+reg for rows n16(+16)
        float biasK = rww * (float)(t - kt);
        float sv[2][4];
#pragma unroll
        for (int rT = 0; rT < 2; ++rT)
#pragma unroll
            for (int q = 0; q < 4; ++q) {
                bool msk = ((padw >> (q * 8)) & 0xFF) != 0;
                sv[rT][q] = msk ? NEGV : (ss[rT][q] + biasK);
            }

        // ---- per-wave partial row max (over this wave's 16 kk)
        float pm[2];
#pragma unroll
        for (int rT = 0; rT < 2; ++rT) {
            float m0 = fmaxf(fmaxf(sv[rT][0], sv[rT][1]), fmaxf(sv[rT][2], sv[rT][3]));
            m0 = fmaxf(m0, __shfl_xor(m0, 16));
            m0 = fmaxf(m0, __shfl_xor(m0, 32));
            pm[rT] = m0;
        }
        if (g == 0) {
            pmax[(0 * 16 + n16) * 4 + w] = pm[0];
            pmax[(1 * 16 + n16) * 4 + w] = pm[1];
        }
        __syncthreads();   // SYNC1

        // ---- (a) stats: combine wave maxima, compute rescale
        if (tid < 32) {
            f32x4 q = *(const f32x4*)(pmax + tid * 4);
            float tm = fmaxf(fmaxf(q[0], q[1]), fmaxf(q[2], q[3]));
            float mo = m_lds[tid];
            float mn = fmaxf(mo, tm);
            sc_lds[tid] = __expf(mo - mn);
            m_lds[tid] = mn;
        }
        __syncthreads();   // SYNC2

        // ---- (b) exp, partial sums, write P (fp16, swizzled)
        float pl[2];
        float p[2][4];
#pragma unroll
        for (int rT = 0; rT < 2; ++rT) {
            float mn = m_lds[rT * 16 + n16];
            float s0 = __expf(sv[rT][0] - mn);
            float s1 = __expf(sv[rT][1] - mn);
            float s2 = __expf(sv[rT][2] - mn);
            float s3 = __expf(sv[rT][3] - mn);
            p[rT][0] = s0; p[rT][1] = s1; p[rT][2] = s2; p[rT][3] = s3;
            float l = s0 + s1 + s2 + s3;
            l += __shfl_xor(l, 16);
            l += __shfl_xor(l, 32);
            pl[rT] = l;
        }
        if (g == 0) {
            psum[(0 * 16 + n16) * 4 + w] = pl[0];
            psum[(1 * 16 + n16) * 4 + w] = pl[1];
        }
#pragma unroll
        for (int rT = 0; rT < 2; ++rT) {
            int r = rT * 16 + n16;
            uint32_t lo = (uint32_t)f2h(p[rT][0]) | ((uint32_t)f2h(p[rT][1]) << 16);
            uint32_t hi = (uint32_t)f2h(p[rT][2]) | ((uint32_t)f2h(p[rT][3]) << 16);
            char* base = (char*)P_lds + r * 128 + (((w * 32 + g * 8)) ^ ((r & 7) << 4));
            *(uint64_t*)base = ((uint64_t)hi << 32) | lo;
        }
        __syncthreads();   // SYNC3

        // ---- (c) running denominator
        if (tid < 32) {
            f32x4 q = *(const f32x4*)(psum + tid * 4);
            l_lds[tid] = l_lds[tid] * sc_lds[tid] + (q[0] + q[1] + q[2] + q[3]);
        }

        // ---- (d) PV: rescale acc rows (g-indexed!), read P A-frags, MFMA
#pragma unroll
        for (int rT = 0; rT < 2; ++rT) {
            f32x4 s4 = *(const f32x4*)(sc_lds + rT * 16 + g * 4);
#pragma unroll
            for (int cT = 0; cT < 2; ++cT) acc[rT][cT] *= s4;
        }
        f16x8 pa[2][2];
#pragma unroll
        for (int rT = 0; rT < 2; ++rT)
#pragma unroll
            for (int ks = 0; ks < 2; ++ks) {
                int r = rT * 16 + n16;
                char* a = (char*)P_lds + r * 128 + (((ks * 64 + g * 16)) ^ ((r & 7) << 4));
                pa[rT][ks] = *(const f16x8*)a;
            }
#pragma unroll
        for (int ks = 0; ks < 2; ++ks)
#pragma unroll
            for (int rT = 0; rT < 2; ++rT)
#pragma unroll
                for (int cT = 0; cT < 2; ++cT)
                    acc[rT][cT] = __builtin_amdgcn_mfma_f32_16x16x32_f16(
                        pa[rT][ks], vb[cT][ks], acc[rT][cT], 0, 0, 0);
        // no trailing sync: next iter's SYNC1 orders P_lds/sc_lds reuse
    }
    __syncthreads();

    // ---- epilogue: divide by l, write out.  acc rows r = rT*16+g*4+reg, col = w*32+cT*16+n16
#pragma unroll
    for (int rT = 0; rT < 2; ++rT) {
        f32x4 lv = *(const f32x4*)(l_lds + rT * 16 + g * 4);
        f32x4 inv;
#pragma unroll
        for (int q = 0; q < 4; ++q) inv[q] = 1.0f / lv[q];
#pragma unroll
        for (int cT = 0; cT < 2; ++cT) {
            int c = w * 32 + cT * 16 + n16;
#pragma unroll
            for (int q = 0; q < 4; ++q) {
                int r = rT * 16 + g * 4 + q;
                out[(size_t)(t * L1_ + l0 + r) * H_ + c] = acc[rT][cT][q] * inv[q];
            }
        }
    }
}

// ---------------------------------------------------------------------------
extern "C" void kernel_launch(void* const* d_in, const int* in_sizes, int n_in,
                              void* d_out, int out_size, void* d_ws, size_t ws_size,
                              hipStream_t stream) {
    const float*   xd   = (const float*)d_in[0];
    const float*   xq   = (const float*)d_in[1];
    const float*   xa   = (const float*)d_in[2];
    const float*   W    = (const float*)d_in[3];
    const float*   bias = (const float*)d_in[4];
    const float*   rw   = (const float*)d_in[5];
    const uint8_t* qm   = (const uint8_t*)d_in[6];
    const uint8_t* am   = (const uint8_t*)d_in[7];
    float* out = (float*)d_out;

    char* ws = (char*)d_ws;
    uint8_t*  pad  = (uint8_t*)ws;                                   // 2 KB
    uint16_t* y_h  = (uint16_t*)(ws + 4096);                         // 512 KB
    uint16_t* dlgT = (uint16_t*)(ws + 4096 + 512 * 1024);            // 512 KB
    uint16_t* xp_h = (uint16_t*)(ws + 4096 + 1024 * 1024);           // 4 MB

    prep_pad_kernel<<<1, 256, 0, stream>>>(qm, am, pad);
    yproj_kernel<<<NK_, 128, 0, stream>>>(xq, xa, W, bias, y_h);
    dlgT_kernel<<<32, 256, 0, stream>>>(xq, xa, dlgT);
    xproj_kernel<<<1024, 256, 0, stream>>>(xd, W, bias, xp_h);
    attn_kernel<<<512, 256, 0, stream>>>(xp_h, y_h, dlgT, pad, rw, out);
}

// Round 5
// 100.137 us; speedup vs baseline: 43.0610x; 1.1478x over previous
//
#include <hip/hip_runtime.h>
#include <stdint.h>

#define NEGV (-1e30f)

constexpr int L1_ = 512;
constexpr int H_  = 128;
constexpr int NK_ = 2048;   // 32 turns * 64 tokens

typedef __attribute__((ext_vector_type(8))) _Float16 f16x8;
typedef __attribute__((ext_vector_type(2))) __fp16   h16x2;
typedef __attribute__((ext_vector_type(4))) float    f32x4;

static __device__ __forceinline__ uint16_t f2h(float x) {
    union { _Float16 h; uint16_t u; } cv; cv.h = (_Float16)x; return cv.u;
}

// ---------------------------------------------------------------------------
// Merged preprocessing kernel, 256 threads/block.
//  blocks [0,1024):    xproj  (16 rows of xd -> fp16 xp_h)
//  blocks [1024,2048): yproj  (2 dialog rows -> fp16 y_h)
//  blocks [2048,2080): dlgT   (transpose one turn -> fp16 dlgT [128][2048])
//  block  2080:        pad    (mask dtype detect -> badd f32[2048] in {0,-1e30})
// ---------------------------------------------------------------------------
__global__ __launch_bounds__(256) void preproc_kernel(
        const float* __restrict__ xd,
        const float* __restrict__ xq,
        const float* __restrict__ xa,
        const float* __restrict__ W,
        const float* __restrict__ bias,
        const uint8_t* __restrict__ qm,
        const uint8_t* __restrict__ am,
        uint16_t* __restrict__ xp_h,
        uint16_t* __restrict__ y_h,
        uint16_t* __restrict__ dlgT,
        float* __restrict__ badd) {
    int b = blockIdx.x;
    int tid = threadIdx.x;
    __shared__ __align__(16) float sbuf[64 * 128];   // 32 KB, carved per branch

    if (b < 1024) {
        // ---- xproj: rows [b*16, b*16+16)
        f32x4* xr4 = (f32x4*)sbuf;
#pragma unroll
        for (int i = 0; i < 2; ++i) {
            int idx = tid + i * 256;
            xr4[idx] = *(const f32x4*)(xd + (size_t)b * 16 * H_ + idx * 4);
        }
        __syncthreads();
        int c = tid & 127, rh = tid >> 7;
        float acc[8];
#pragma unroll
        for (int i = 0; i < 8; ++i) acc[i] = 0.0f;
        const f32x4* w4 = (const f32x4*)(W + (size_t)c * H_);
        for (int d4 = 0; d4 < 32; ++d4) {
            f32x4 wv = w4[d4];
#pragma unroll
            for (int i = 0; i < 8; ++i) {
                f32x4 x = xr4[(rh * 8 + i) * 32 + d4];
                acc[i] += wv[0]*x[0] + wv[1]*x[1] + wv[2]*x[2] + wv[3]*x[3];
            }
        }
        float bc = bias[c];
#pragma unroll
        for (int i = 0; i < 8; ++i)
            xp_h[(size_t)(b * 16 + rh * 8 + i) * H_ + c] = f2h(fmaxf(acc[i] + bc, 0.0f));
    } else if (b < 2048) {
        // ---- yproj: rows k0, k0+1
        int k0 = (b - 1024) * 2;
        int half = tid >> 7, c = tid & 127;
        int k = k0 + half;
        int b2 = k >> 6, r = k & 63;
        const float* src = (r < 32) ? (xq + (size_t)(b2 * 32 + r) * H_)
                                    : (xa + (size_t)(b2 * 32 + (r - 32)) * H_);
        float* row = sbuf + half * H_;
        row[c] = src[c];
        __syncthreads();
        float acc = bias[c];
        const f32x4* w4 = (const f32x4*)(W + (size_t)c * H_);
        const f32x4* x4 = (const f32x4*)row;
#pragma unroll
        for (int d4 = 0; d4 < 32; ++d4) {
            f32x4 wv = w4[d4], x = x4[d4];
            acc += wv[0]*x[0] + wv[1]*x[1] + wv[2]*x[2] + wv[3]*x[3];
        }
        y_h[(size_t)k * H_ + c] = f2h(fmaxf(acc, 0.0f));
    } else if (b < 2080) {
        // ---- dlgT: turn b2, 64 rows x 128 cols -> dlgT[c][b2*64 + kk]
        int b2 = b - 2048;
        f32x4* ld4 = (f32x4*)sbuf;
#pragma unroll
        for (int i = 0; i < 8; ++i) {
            int idx = tid + i * 256;
            int row = idx >> 5, d4 = idx & 31;
            const float* src = (row < 32) ? (xq + (size_t)(b2 * 32 + row) * H_)
                                          : (xa + (size_t)(b2 * 32 + row - 32) * H_);
            ld4[idx] = *(const f32x4*)(src + d4 * 4);
        }
        __syncthreads();
        int c = tid & 127, half = tid >> 7;
        uint32_t u[16];
#pragma unroll
        for (int j2 = 0; j2 < 16; ++j2) {
            float v0 = sbuf[(half * 32 + 2 * j2) * H_ + c];
            float v1 = sbuf[(half * 32 + 2 * j2 + 1) * H_ + c];
            u[j2] = (uint32_t)f2h(v0) | ((uint32_t)f2h(v1) << 16);
        }
        uint32_t* dst = (uint32_t*)(dlgT + (size_t)c * NK_ + b2 * 64 + half * 32);
#pragma unroll
        for (int j2 = 0; j2 < 16; ++j2) dst[j2] = u[j2];
    } else {
        // ---- pad detection + badd
        int* flags = (int*)sbuf;
        if (tid == 0) { flags[0] = 0; flags[1] = 0; }
        __syncthreads();
        uint32_t v = ((const uint32_t*)qm)[tid] | ((const uint32_t*)am)[tid];
        if (v & 0xFFu)        atomicOr(&flags[0], 1);
        if (v & 0xFFFFFF00u)  atomicOr(&flags[1], 1);
        __syncthreads();
        int f0 = flags[0], f1 = flags[1];
        int mode = (f0 && !f1) ? 0 : ((!f0 && f1) ? 1 : 2);
        for (int k = tid; k < NK_; k += 256) {
            int b2 = k >> 6, r = k & 63;
            int idx = b2 * 32 + (r < 32 ? r : r - 32);
            const uint8_t* src = (r < 32) ? qm : am;
            int p;
            if (mode == 0)      p = (((const int*)src)[idx] != 0);
            else if (mode == 1) p = (((const float*)src)[idx] != 0.0f);
            else                p = (src[idx] != 0);
            badd[k] = p ? NEGV : 0.0f;
        }
    }
}

// ---------------------------------------------------------------------------
// Flash attention: per-wave-independent k-tiles, no barriers in main loop.
// Block = (t, 32 l-rows), 4 waves; wave w handles kt = w, w+4, ...
// S^T = y . x^T per tile (64 kk x 32 r), P in per-wave LDS, PV to 32x128 acc.
// ---------------------------------------------------------------------------
__global__ __launch_bounds__(256, 2) void attn_kernel(
        const uint16_t* __restrict__ xp_h,
        const uint16_t* __restrict__ y_h,
        const uint16_t* __restrict__ dlgT,
        const float*    __restrict__ badd,
        const float*    __restrict__ rw,
        float* __restrict__ out) {
    int bid = blockIdx.x;
    // pairing: CU ci hosts jobs (2*ci, 2*ci+1) -> both blocks have adjacent t
    int j  = ((bid & 255) << 1) | (bid >> 8);
    int t  = 31 - (j >> 4);
    int l0 = (j & 15) << 5;
    int tid = threadIdx.x;

    __shared__ __align__(16) float smem[4 * 64 * 64];   // 64 KB: P (16 KB) then Obuf
    __shared__ float stats_m[4][32];
    __shared__ float stats_l[4][32];

    if (t == 0) {                  // zero_first
        f32x4 z = {0.f, 0.f, 0.f, 0.f};
        f32x4* o4 = (f32x4*)(out + (size_t)l0 * H_);
        for (int i = tid; i < 32 * H_ / 4; i += 256) o4[i] = z;
        return;
    }

    int w = tid >> 6, lane = tid & 63, n16 = lane & 15, g = lane >> 4;
    int prow0 = n16, prow1 = 16 + n16;
    int swz0 = (prow0 & 7) << 4, swz1 = (prow1 & 7) << 4;   // same value, kept explicit

    // x fragments (same for all waves)
    f16x8 xf[2][4];
#pragma unroll
    for (int rT = 0; rT < 2; ++rT)
#pragma unroll
        for (int ks = 0; ks < 4; ++ks)
            xf[rT][ks] = *(const f16x8*)(xp_h + (size_t)(t * L1_ + l0 + rT * 16 + n16) * H_ + ks * 32 + g * 8);

    f32x4 zero4 = {0.f, 0.f, 0.f, 0.f};
    f32x4 acc[2][8];
#pragma unroll
    for (int a = 0; a < 2; ++a)
#pragma unroll
        for (int c = 0; c < 8; ++c) acc[a][c] = zero4;

    float m_r[2] = {-INFINITY, -INFINITY};
    float l_r[2] = {0.0f, 0.0f};
    float rww = rw[0];

    char* Pw = (char*)smem + w * 4096;     // per-wave 4 KB P buffer (32 rows x 128 B)

    for (int kt = w; kt < t; kt += 4) {
        const uint16_t* ybase = y_h + (size_t)kt * 64 * H_;
        f32x4 ss[4][2];
#pragma unroll
        for (int kkT = 0; kkT < 4; ++kkT) { ss[kkT][0] = zero4; ss[kkT][1] = zero4; }

        // ---- S^T: 32 MFMAs, yf staged per-ks (16 VGPR live)
#pragma unroll
        for (int ks = 0; ks < 4; ++ks) {
            f16x8 yf[4];
#pragma unroll
            for (int kkT = 0; kkT < 4; ++kkT)
                yf[kkT] = *(const f16x8*)(ybase + (size_t)(kkT * 16 + n16) * H_ + ks * 32 + g * 8);
#pragma unroll
            for (int kkT = 0; kkT < 4; ++kkT) {
                ss[kkT][0] = __builtin_amdgcn_mfma_f32_16x16x32_f16(yf[kkT], xf[0][ks], ss[kkT][0], 0, 0, 0);
                ss[kkT][1] = __builtin_amdgcn_mfma_f32_16x16x32_f16(yf[kkT], xf[1][ks], ss[kkT][1], 0, 0, 0);
            }
        }

        // ---- mask + recency bias (badd[kk] in {0,-1e30}, bias row-independent)
        float biasK = rww * (float)(t - kt);
#pragma unroll
        for (int kkT = 0; kkT < 4; ++kkT) {
            f32x4 ba = *(const f32x4*)(badd + kt * 64 + kkT * 16 + g * 4);
            ba += biasK;
            ss[kkT][0] += ba;
            ss[kkT][1] += ba;
        }

        // ---- per-row online max (16 in-lane values + cross-g shfl reduce)
        float sc[2];
#pragma unroll
        for (int rT = 0; rT < 2; ++rT) {
            f32x4 mx4 = ss[0][rT];
#pragma unroll
            for (int kkT = 1; kkT < 4; ++kkT) {
                mx4[0] = fmaxf(mx4[0], ss[kkT][rT][0]);
                mx4[1] = fmaxf(mx4[1], ss[kkT][rT][1]);
                mx4[2] = fmaxf(mx4[2], ss[kkT][rT][2]);
                mx4[3] = fmaxf(mx4[3], ss[kkT][rT][3]);
            }
            float mx = fmaxf(fmaxf(mx4[0], mx4[1]), fmaxf(mx4[2], mx4[3]));
            mx = fmaxf(mx, __shfl_xor(mx, 16));
            mx = fmaxf(mx, __shfl_xor(mx, 32));
            float mn = fmaxf(m_r[rT], mx);
            sc[rT] = __expf(m_r[rT] - mn);     // 0 on first tile (exp(-inf))
            m_r[rT] = mn;
        }

        // ---- P = exp(s - m), partial sums, write P to wave-local LDS (swizzled)
#pragma unroll
        for (int rT = 0; rT < 2; ++rT) {
            int r = rT ? prow1 : prow0;
            int swz = rT ? swz1 : swz0;
            float mn = m_r[rT];
            float ps = 0.0f;
#pragma unroll
            for (int kkT = 0; kkT < 4; ++kkT) {
                f32x4 p;
#pragma unroll
                for (int q = 0; q < 4; ++q) p[q] = __expf(ss[kkT][rT][q] - mn);
                ps += (p[0] + p[1]) + (p[2] + p[3]);
                union { h16x2 h2[2]; uint64_t u64; } pk;
                pk.h2[0] = __builtin_amdgcn_cvt_pkrtz(p[0], p[1]);
                pk.h2[1] = __builtin_amdgcn_cvt_pkrtz(p[2], p[3]);
                *(uint64_t*)(Pw + r * 128 + ((kkT * 32 + g * 8) ^ swz)) = pk.u64;
            }
            ps += __shfl_xor(ps, 16);
            ps += __shfl_xor(ps, 32);
            l_r[rT] = l_r[rT] * sc[rT] + ps;
        }

        // wave-local LDS visibility (write -> read, same wave, no barrier needed)
        asm volatile("s_waitcnt lgkmcnt(0)" ::: "memory");

        // ---- rescale O accumulator (skip when max didn't move, common case)
        if (!__all((sc[0] == 1.0f) && (sc[1] == 1.0f))) {
#pragma unroll
            for (int rT = 0; rT < 2; ++rT) {
                f32x4 s4;
#pragma unroll
                for (int q = 0; q < 4; ++q) s4[q] = __shfl(sc[rT], (g << 2) + q);
#pragma unroll
                for (int cT = 0; cT < 8; ++cT) acc[rT][cT] *= s4;
            }
        }

        // ---- PV: read P A-frags, stream dlgT B-frags, 32 MFMAs
        f16x8 pa[2][2];
#pragma unroll
        for (int rT = 0; rT < 2; ++rT) {
            int r = rT ? prow1 : prow0;
            int swz = rT ? swz1 : swz0;
#pragma unroll
            for (int ks = 0; ks < 2; ++ks)
                pa[rT][ks] = *(const f16x8*)(Pw + r * 128 + ((ks * 64 + g * 16) ^ swz));
        }
        const uint16_t* vbase = dlgT + kt * 64;
#pragma unroll
        for (int cT = 0; cT < 8; ++cT) {
            const uint16_t* vrow = vbase + (size_t)(cT * 16 + n16) * NK_;
            f16x8 vb0 = *(const f16x8*)(vrow + g * 8);
            f16x8 vb1 = *(const f16x8*)(vrow + 32 + g * 8);
#pragma unroll
            for (int rT = 0; rT < 2; ++rT) {
                acc[rT][cT] = __builtin_amdgcn_mfma_f32_16x16x32_f16(pa[rT][0], vb0, acc[rT][cT], 0, 0, 0);
                acc[rT][cT] = __builtin_amdgcn_mfma_f32_16x16x32_f16(pa[rT][1], vb1, acc[rT][cT], 0, 0, 0);
            }
        }
    }

    // ---- cross-wave combine (the only barriers in the kernel)
    if (g == 0) {
        stats_m[w][n16]      = m_r[0];
        stats_m[w][16 + n16] = m_r[1];
        stats_l[w][n16]      = l_r[0];
        stats_l[w][16 + n16] = l_r[1];
    }
    __syncthreads();

    float fac[2][4];
#pragma unroll
    for (int rT = 0; rT < 2; ++rT)
#pragma unroll
        for (int q = 0; q < 4; ++q) {
            int r = rT * 16 + (g << 2) + q;
            float m0 = stats_m[0][r], m1 = stats_m[1][r];
            float m2 = stats_m[2][r], m3 = stats_m[3][r];
            float mf = fmaxf(fmaxf(m0, m1), fmaxf(m2, m3));
            float lf = stats_l[0][r] * __expf(m0 - mf) + stats_l[1][r] * __expf(m1 - mf)
                     + stats_l[2][r] * __expf(m2 - mf) + stats_l[3][r] * __expf(m3 - mf);
            float mw = stats_m[w][r];
            fac[rT][q] = __expf(mw - mf) / lf;    // 0 for tile-less waves (mw = -inf)
        }

    // write scaled partials: Obuf[w][slot][lane], slot = (rT*8+cT)*4+q
    float* Ob = smem + w * 4096;
#pragma unroll
    for (int rT = 0; rT < 2; ++rT)
#pragma unroll
        for (int cT = 0; cT < 8; ++cT)
#pragma unroll
            for (int q = 0; q < 4; ++q)
                Ob[((rT * 8 + cT) * 4 + q) * 64 + lane] = acc[rT][cT][q] * fac[rT][q];
    __syncthreads();

    // wave w reduces slots [w*16, w*16+16) across the 4 wave-buffers and stores
    size_t obase = (size_t)(t * L1_ + l0) * H_;
#pragma unroll
    for (int s = 0; s < 16; ++s) {
        int slot = w * 16 + s;
        float v = smem[slot * 64 + lane] + smem[4096 + slot * 64 + lane]
                + smem[8192 + slot * 64 + lane] + smem[12288 + slot * 64 + lane];
        int rT = slot >> 5, cT = (slot >> 2) & 7, q = slot & 3;
        out[obase + (size_t)(rT * 16 + (g << 2) + q) * H_ + cT * 16 + n16] = v;
    }
}

// ---------------------------------------------------------------------------
extern "C" void kernel_launch(void* const* d_in, const int* in_sizes, int n_in,
                              void* d_out, int out_size, void* d_ws, size_t ws_size,
                              hipStream_t stream) {
    const float*   xd   = (const float*)d_in[0];
    const float*   xq   = (const float*)d_in[1];
    const float*   xa   = (const float*)d_in[2];
    const float*   W    = (const float*)d_in[3];
    const float*   bias = (const float*)d_in[4];
    const float*   rw   = (const float*)d_in[5];
    const uint8_t* qm   = (const uint8_t*)d_in[6];
    const uint8_t* am   = (const uint8_t*)d_in[7];
    float* out = (float*)d_out;

    char* ws = (char*)d_ws;
    float*    badd = (float*)ws;                                  // 8 KB
    uint16_t* y_h  = (uint16_t*)(ws + 8192);                      // 512 KB
    uint16_t* dlgT = (uint16_t*)(ws + 8192 + 524288);             // 512 KB
    uint16_t* xp_h = (uint16_t*)(ws + 8192 + 2 * 524288);         // 4 MB

    preproc_kernel<<<2081, 256, 0, stream>>>(xd, xq, xa, W, bias, qm, am,
                                             xp_h, y_h, dlgT, badd);
    attn_kernel<<<512, 256, 0, stream>>>(xp_h, y_h, dlgT, badd, rw, out);
}

// Round 6
// 66.694 us; speedup vs baseline: 64.6531x; 1.5014x over previous
//
#include <hip/hip_runtime.h>
#include <stdint.h>

#define NEGV (-1e30f)

constexpr int L1_ = 512;
constexpr int H_  = 128;
constexpr int NK_ = 2048;   // 32 turns * 64 tokens

typedef __attribute__((ext_vector_type(8))) _Float16 f16x8;
typedef __attribute__((ext_vector_type(2))) __fp16   h16x2;
typedef __attribute__((ext_vector_type(4))) float    f32x4;

static __device__ __forceinline__ uint16_t f2h(float x) {
    union { _Float16 h; uint16_t u; } cv; cv.h = (_Float16)x; return cv.u;
}

// Fragment-major layouts (16B chunk per lane, lane = (g<<4)|n16):
//  X2[lb(512)][rT(2)][ks(4)][lane]  chunk = xp[lb*32+rT*16+n16][ks*32+g*8 .. +8]
//  Y2[kt(32)][kkT(4)][ks(4)][lane]  chunk = yp[kt*64+kkT*16+n16][ks*32+g*8 .. +8]
//  V2[kt(32)][cT(8)][ks(2)][lane]   chunk = dlg[kt*64+ks*32+g*8+j][cT*16+n16]
// Every hot-loop load: base + lane*16 -> one coalesced 1KB dwordx4 per wave.

// ---------------------------------------------------------------------------
// Merged preprocessing kernel, 256 threads/block.
//  [0,1024):    xproj  -> X2   (16 rows each; lb = b>>1, rT = b&1)
//  [1024,1152): yproj  -> Y2   (16 rows each; kt = (b-1024)>>2, kkT = (b-1024)&3)
//  [1152,1184): dlg    -> V2   (one turn kt = b-1152)
//  1184:        masks  -> badd f32[2048] in {0,-1e30}
// ---------------------------------------------------------------------------
__global__ __launch_bounds__(256) void preproc_kernel(
        const float* __restrict__ xd,
        const float* __restrict__ xq,
        const float* __restrict__ xa,
        const float* __restrict__ W,
        const float* __restrict__ bias,
        const uint8_t* __restrict__ qm,
        const uint8_t* __restrict__ am,
        uint8_t* __restrict__ X2,
        uint8_t* __restrict__ Y2,
        uint8_t* __restrict__ V2,
        float* __restrict__ badd) {
    int b = blockIdx.x;
    int tid = threadIdx.x;
    __shared__ __align__(16) float sbuf[64 * 128];   // 32 KB

    if (b < 1152) {
        // ---- projection: 16 rows -> relu(row @ W.T + b), then fragment-pack
        bool isx = (b < 1024);
        int kb = b - 1024;
        f32x4* xr4 = (f32x4*)sbuf;
        if (isx) {
#pragma unroll
            for (int i = 0; i < 2; ++i) {
                int idx = tid + i * 256;
                xr4[idx] = *(const f32x4*)(xd + (size_t)b * 16 * H_ + idx * 4);
            }
        } else {
            int k0 = kb * 16;
#pragma unroll
            for (int i = 0; i < 2; ++i) {
                int idx = tid + i * 256;
                int row = idx >> 5, d4 = idx & 31;
                int k = k0 + row;
                int b2 = k >> 6, r = k & 63;
                const float* src = (r < 32) ? (xq + (size_t)(b2 * 32 + r) * H_)
                                            : (xa + (size_t)(b2 * 32 + (r - 32)) * H_);
                xr4[idx] = *(const f32x4*)(src + d4 * 4);
            }
        }
        __syncthreads();
        int c = tid & 127, rh = tid >> 7;
        float acc[8];
#pragma unroll
        for (int i = 0; i < 8; ++i) acc[i] = 0.0f;
        const f32x4* w4 = (const f32x4*)(W + (size_t)c * H_);
        for (int d4 = 0; d4 < 32; ++d4) {
            f32x4 wv = w4[d4];
#pragma unroll
            for (int i = 0; i < 8; ++i) {
                f32x4 x = xr4[(rh * 8 + i) * 32 + d4];
                acc[i] += wv[0]*x[0] + wv[1]*x[1] + wv[2]*x[2] + wv[3]*x[3];
            }
        }
        float bc = bias[c];
        float* res = sbuf + 2048;     // results region (8 KB)
#pragma unroll
        for (int i = 0; i < 8; ++i)
            res[(rh * 8 + i) * H_ + c] = fmaxf(acc[i] + bc, 0.0f);
        __syncthreads();
        // pack: thread tid -> chunk (ks = tid>>6, lane = tid&63)
        int ks = tid >> 6, l = tid & 63, n16 = l & 15, g = l >> 4;
        uint16_t hbuf[8];
#pragma unroll
        for (int j = 0; j < 8; ++j)
            hbuf[j] = f2h(res[n16 * H_ + ks * 32 + g * 8 + j]);
        uint8_t* dst;
        if (isx) dst = X2 + (((size_t)b * 4 + ks) << 10) + l * 16;          // (lb*2+rT)=b
        else     dst = Y2 + (((size_t)kb * 4 + ks) << 10) + l * 16;         // (kt*4+kkT)=kb
        *(uint64_t*)dst       = ((const uint64_t*)hbuf)[0];
        *(uint64_t*)(dst + 8) = ((const uint64_t*)hbuf)[1];
    } else if (b < 1184) {
        // ---- V2: turn kt, 64 dialog rows f32 in LDS, pack transposed chunks
        int kt = b - 1152;
        f32x4* ld4 = (f32x4*)sbuf;
#pragma unroll
        for (int i = 0; i < 8; ++i) {
            int idx = tid + i * 256;
            int row = idx >> 5, d4 = idx & 31;
            const float* src = (row < 32) ? (xq + (size_t)(kt * 32 + row) * H_)
                                          : (xa + (size_t)(kt * 32 + row - 32) * H_);
            ld4[idx] = *(const f32x4*)(src + d4 * 4);
        }
        __syncthreads();
#pragma unroll
        for (int i = 0; i < 4; ++i) {
            int id = tid + i * 256;            // (cT*2+ks)*64 + lane
            int cT = id >> 7, ks = (id >> 6) & 1, l = id & 63;
            int n16 = l & 15, g = l >> 4;
            uint16_t hbuf[8];
#pragma unroll
            for (int j = 0; j < 8; ++j)
                hbuf[j] = f2h(sbuf[(ks * 32 + g * 8 + j) * H_ + cT * 16 + n16]);
            uint8_t* dst = V2 + (((size_t)kt * 16 + cT * 2 + ks) << 10) + l * 16;
            *(uint64_t*)dst       = ((const uint64_t*)hbuf)[0];
            *(uint64_t*)(dst + 8) = ((const uint64_t*)hbuf)[1];
        }
    } else {
        // ---- pad detection + badd
        int* flags = (int*)sbuf;
        if (tid == 0) { flags[0] = 0; flags[1] = 0; }
        __syncthreads();
        uint32_t v = ((const uint32_t*)qm)[tid] | ((const uint32_t*)am)[tid];
        if (v & 0xFFu)        atomicOr(&flags[0], 1);
        if (v & 0xFFFFFF00u)  atomicOr(&flags[1], 1);
        __syncthreads();
        int f0 = flags[0], f1 = flags[1];
        int mode = (f0 && !f1) ? 0 : ((!f0 && f1) ? 1 : 2);
        for (int k = tid; k < NK_; k += 256) {
            int b2 = k >> 6, r = k & 63;
            int idx = b2 * 32 + (r < 32 ? r : r - 32);
            const uint8_t* src = (r < 32) ? qm : am;
            int p;
            if (mode == 0)      p = (((const int*)src)[idx] != 0);
            else if (mode == 1) p = (((const float*)src)[idx] != 0.0f);
            else                p = (src[idx] != 0);
            badd[k] = p ? NEGV : 0.0f;
        }
    }
}

// ---------------------------------------------------------------------------
// Flash attention: per-wave-independent k-tiles, no barriers in main loop.
// All global loads fully coalesced via fragment-major X2/Y2/V2.
// bid<256 -> t = 31-(bid>>4); bid>=256 -> t = (bid-256)>>4  ((t,31-t) per CU)
// ---------------------------------------------------------------------------
__global__ __launch_bounds__(256, 2) void attn_kernel(
        const uint8_t* __restrict__ X2,
        const uint8_t* __restrict__ Y2,
        const uint8_t* __restrict__ V2,
        const float*   __restrict__ badd,
        const float*   __restrict__ rw,
        float* __restrict__ out) {
    int bid = blockIdx.x;
    int t  = (bid < 256) ? (31 - (bid >> 4)) : ((bid - 256) >> 4);
    int l0 = (bid & 15) << 5;
    int tid = threadIdx.x;

    __shared__ __align__(16) float smem[4 * 64 * 64];   // 64 KB: P (16 KB) then Obuf
    __shared__ float stats_m[4][32];
    __shared__ float stats_l[4][32];

    if (t == 0) {                  // zero_first
        f32x4 z = {0.f, 0.f, 0.f, 0.f};
        f32x4* o4 = (f32x4*)(out + (size_t)l0 * H_);
        for (int i = tid; i < 32 * H_ / 4; i += 256) o4[i] = z;
        return;
    }

    int w = tid >> 6, lane = tid & 63, n16 = lane & 15, g = lane >> 4;
    int prow0 = n16, prow1 = 16 + n16;
    int swz = (n16 & 7) << 4;

    // x fragments: 8 coalesced loads
    f16x8 xf[2][4];
    {
        const uint8_t* xbase = X2 + (((size_t)(t * 16 + (l0 >> 5)) * 8) << 10) + lane * 16;
#pragma unroll
        for (int rT = 0; rT < 2; ++rT)
#pragma unroll
            for (int ks = 0; ks < 4; ++ks)
                xf[rT][ks] = *(const f16x8*)(xbase + ((rT * 4 + ks) << 10));
    }

    f32x4 zero4 = {0.f, 0.f, 0.f, 0.f};
    f32x4 acc[2][8];
#pragma unroll
    for (int a = 0; a < 2; ++a)
#pragma unroll
        for (int c = 0; c < 8; ++c) acc[a][c] = zero4;

    float m_r[2] = {-INFINITY, -INFINITY};
    float l_r[2] = {0.0f, 0.0f};
    float rww = rw[0];

    char* Pw = (char*)smem + w * 4096;     // per-wave 4 KB P buffer

    for (int kt = w; kt < t; kt += 4) {
        const uint8_t* ybase = Y2 + ((size_t)kt << 14) + lane * 16;
        f32x4 ss[4][2];
#pragma unroll
        for (int kkT = 0; kkT < 4; ++kkT) { ss[kkT][0] = zero4; ss[kkT][1] = zero4; }

        // ---- S^T: 32 MFMAs, 16 coalesced y loads
#pragma unroll
        for (int ks = 0; ks < 4; ++ks) {
            f16x8 yf[4];
#pragma unroll
            for (int kkT = 0; kkT < 4; ++kkT)
                yf[kkT] = *(const f16x8*)(ybase + ((kkT * 4 + ks) << 10));
#pragma unroll
            for (int kkT = 0; kkT < 4; ++kkT) {
                ss[kkT][0] = __builtin_amdgcn_mfma_f32_16x16x32_f16(yf[kkT], xf[0][ks], ss[kkT][0], 0, 0, 0);
                ss[kkT][1] = __builtin_amdgcn_mfma_f32_16x16x32_f16(yf[kkT], xf[1][ks], ss[kkT][1], 0, 0, 0);
            }
        }

        // ---- mask + recency bias
        float biasK = rww * (float)(t - kt);
#pragma unroll
        for (int kkT = 0; kkT < 4; ++kkT) {
            f32x4 ba = *(const f32x4*)(badd + kt * 64 + kkT * 16 + g * 4);
            ba += biasK;
            ss[kkT][0] += ba;
            ss[kkT][1] += ba;
        }

        // ---- per-row online max
        float sc[2];
#pragma unroll
        for (int rT = 0; rT < 2; ++rT) {
            f32x4 mx4 = ss[0][rT];
#pragma unroll
            for (int kkT = 1; kkT < 4; ++kkT) {
                mx4[0] = fmaxf(mx4[0], ss[kkT][rT][0]);
                mx4[1] = fmaxf(mx4[1], ss[kkT][rT][1]);
                mx4[2] = fmaxf(mx4[2], ss[kkT][rT][2]);
                mx4[3] = fmaxf(mx4[3], ss[kkT][rT][3]);
            }
            float mx = fmaxf(fmaxf(mx4[0], mx4[1]), fmaxf(mx4[2], mx4[3]));
            mx = fmaxf(mx, __shfl_xor(mx, 16));
            mx = fmaxf(mx, __shfl_xor(mx, 32));
            float mn = fmaxf(m_r[rT], mx);
            sc[rT] = __expf(m_r[rT] - mn);
            m_r[rT] = mn;
        }

        // ---- P = exp(s - m), partial sums, write P to wave-local LDS
#pragma unroll
        for (int rT = 0; rT < 2; ++rT) {
            int r = rT ? prow1 : prow0;
            float mn = m_r[rT];
            float ps = 0.0f;
#pragma unroll
            for (int kkT = 0; kkT < 4; ++kkT) {
                f32x4 p;
#pragma unroll
                for (int q = 0; q < 4; ++q) p[q] = __expf(ss[kkT][rT][q] - mn);
                ps += (p[0] + p[1]) + (p[2] + p[3]);
                union { h16x2 h2[2]; uint64_t u64; } pk;
                pk.h2[0] = __builtin_amdgcn_cvt_pkrtz(p[0], p[1]);
                pk.h2[1] = __builtin_amdgcn_cvt_pkrtz(p[2], p[3]);
                *(uint64_t*)(Pw + r * 128 + ((kkT * 32 + g * 8) ^ swz)) = pk.u64;
            }
            ps += __shfl_xor(ps, 16);
            ps += __shfl_xor(ps, 32);
            l_r[rT] = l_r[rT] * sc[rT] + ps;
        }

        asm volatile("s_waitcnt lgkmcnt(0)" ::: "memory");

        // ---- rescale O accumulator (skip when max didn't move)
        if (!__all((sc[0] == 1.0f) && (sc[1] == 1.0f))) {
#pragma unroll
            for (int rT = 0; rT < 2; ++rT) {
                f32x4 s4;
#pragma unroll
                for (int q = 0; q < 4; ++q) s4[q] = __shfl(sc[rT], (g << 2) + q);
#pragma unroll
                for (int cT = 0; cT < 8; ++cT) acc[rT][cT] *= s4;
            }
        }

        // ---- PV: P A-frags from LDS, 16 coalesced v loads, 32 MFMAs
        f16x8 pa[2][2];
#pragma unroll
        for (int rT = 0; rT < 2; ++rT) {
            int r = rT ? prow1 : prow0;
#pragma unroll
            for (int ks = 0; ks < 2; ++ks)
                pa[rT][ks] = *(const f16x8*)(Pw + r * 128 + ((ks * 64 + g * 16) ^ swz));
        }
        const uint8_t* vbase = V2 + ((size_t)kt << 14) + lane * 16;
#pragma unroll
        for (int cT = 0; cT < 8; ++cT) {
            f16x8 vb0 = *(const f16x8*)(vbase + ((cT * 2) << 10));
            f16x8 vb1 = *(const f16x8*)(vbase + ((cT * 2 + 1) << 10));
#pragma unroll
            for (int rT = 0; rT < 2; ++rT) {
                acc[rT][cT] = __builtin_amdgcn_mfma_f32_16x16x32_f16(pa[rT][0], vb0, acc[rT][cT], 0, 0, 0);
                acc[rT][cT] = __builtin_amdgcn_mfma_f32_16x16x32_f16(pa[rT][1], vb1, acc[rT][cT], 0, 0, 0);
            }
        }
    }

    // ---- cross-wave combine
    if (g == 0) {
        stats_m[w][n16]      = m_r[0];
        stats_m[w][16 + n16] = m_r[1];
        stats_l[w][n16]      = l_r[0];
        stats_l[w][16 + n16] = l_r[1];
    }
    __syncthreads();

    float fac[2][4];
#pragma unroll
    for (int rT = 0; rT < 2; ++rT)
#pragma unroll
        for (int q = 0; q < 4; ++q) {
            int r = rT * 16 + (g << 2) + q;
            float m0 = stats_m[0][r], m1 = stats_m[1][r];
            float m2 = stats_m[2][r], m3 = stats_m[3][r];
            float mf = fmaxf(fmaxf(m0, m1), fmaxf(m2, m3));
            float lf = stats_l[0][r] * __expf(m0 - mf) + stats_l[1][r] * __expf(m1 - mf)
                     + stats_l[2][r] * __expf(m2 - mf) + stats_l[3][r] * __expf(m3 - mf);
            float mw = stats_m[w][r];
            fac[rT][q] = __expf(mw - mf) / lf;
        }

    float* Ob = smem + w * 4096;
#pragma unroll
    for (int rT = 0; rT < 2; ++rT)
#pragma unroll
        for (int cT = 0; cT < 8; ++cT)
#pragma unroll
            for (int q = 0; q < 4; ++q)
                Ob[((rT * 8 + cT) * 4 + q) * 64 + lane] = acc[rT][cT][q] * fac[rT][q];
    __syncthreads();

    size_t obase = (size_t)(t * L1_ + l0) * H_;
#pragma unroll
    for (int s = 0; s < 16; ++s) {
        int slot = w * 16 + s;
        float v = smem[slot * 64 + lane] + smem[4096 + slot * 64 + lane]
                + smem[8192 + slot * 64 + lane] + smem[12288 + slot * 64 + lane];
        int rT = slot >> 5, cT = (slot >> 2) & 7, q = slot & 3;
        out[obase + (size_t)(rT * 16 + (g << 2) + q) * H_ + cT * 16 + n16] = v;
    }
}

// ---------------------------------------------------------------------------
extern "C" void kernel_launch(void* const* d_in, const int* in_sizes, int n_in,
                              void* d_out, int out_size, void* d_ws, size_t ws_size,
                              hipStream_t stream) {
    const float*   xd   = (const float*)d_in[0];
    const float*   xq   = (const float*)d_in[1];
    const float*   xa   = (const float*)d_in[2];
    const float*   W    = (const float*)d_in[3];
    const float*   bias = (const float*)d_in[4];
    const float*   rw   = (const float*)d_in[5];
    const uint8_t* qm   = (const uint8_t*)d_in[6];
    const uint8_t* am   = (const uint8_t*)d_in[7];
    float* out = (float*)d_out;

    char* ws = (char*)d_ws;
    float*   badd = (float*)ws;                          // 8 KB
    uint8_t* Y2   = (uint8_t*)(ws + 8192);               // 512 KB
    uint8_t* V2   = (uint8_t*)(ws + 8192 + 524288);      // 512 KB
    uint8_t* X2   = (uint8_t*)(ws + 8192 + 2 * 524288);  // 4 MB

    preproc_kernel<<<1185, 256, 0, stream>>>(xd, xq, xa, W, bias, qm, am,
                                             X2, Y2, V2, badd);
    attn_kernel<<<512, 256, 0, stream>>>(X2, Y2, V2, badd, rw, out);
}

// Round 7
// 49.737 us; speedup vs baseline: 86.6958x; 1.3409x over previous
//
#include <hip/hip_runtime.h>
#include <stdint.h>

#define NEGV (-1e30f)

constexpr int L1_ = 512;
constexpr int H_  = 128;
constexpr int NK_ = 2048;   // 32 turns * 64 tokens

typedef __attribute__((ext_vector_type(8))) _Float16 f16x8;
typedef __attribute__((ext_vector_type(2))) __fp16   h16x2;
typedef __attribute__((ext_vector_type(4))) float    f32x4;

static __device__ __forceinline__ uint16_t f2h(float x) {
    union { _Float16 h; uint16_t u; } cv; cv.h = (_Float16)x; return cv.u;
}

// Fragment-major layouts (16B chunk per lane, lane = (g<<4)|n16):
//  X2[lb(512)][rT(2)][ks(4)][lane]  chunk = xp[lb*32+rT*16+n16][ks*32+g*8 .. +8]
//  Y2[kt(32)][kkT(4)][ks(4)][lane]  chunk = yp[kt*64+kkT*16+n16][ks*32+g*8 .. +8]
//  V2[kt(32)][cT(8)][ks(2)][lane]   chunk = dlg[kt*64+ks*32+g*8+j][cT*16+n16]
// Every hot-loop load: base + lane*16 -> one coalesced 1KB dwordx4 per wave.

// ---------------------------------------------------------------------------
// Merged preprocessing kernel, 256 threads/block. (unchanged from R6)
// ---------------------------------------------------------------------------
__global__ __launch_bounds__(256) void preproc_kernel(
        const float* __restrict__ xd,
        const float* __restrict__ xq,
        const float* __restrict__ xa,
        const float* __restrict__ W,
        const float* __restrict__ bias,
        const uint8_t* __restrict__ qm,
        const uint8_t* __restrict__ am,
        uint8_t* __restrict__ X2,
        uint8_t* __restrict__ Y2,
        uint8_t* __restrict__ V2,
        float* __restrict__ badd) {
    int b = blockIdx.x;
    int tid = threadIdx.x;
    __shared__ __align__(16) float sbuf[64 * 128];   // 32 KB

    if (b < 1152) {
        bool isx = (b < 1024);
        int kb = b - 1024;
        f32x4* xr4 = (f32x4*)sbuf;
        if (isx) {
#pragma unroll
            for (int i = 0; i < 2; ++i) {
                int idx = tid + i * 256;
                xr4[idx] = *(const f32x4*)(xd + (size_t)b * 16 * H_ + idx * 4);
            }
        } else {
            int k0 = kb * 16;
#pragma unroll
            for (int i = 0; i < 2; ++i) {
                int idx = tid + i * 256;
                int row = idx >> 5, d4 = idx & 31;
                int k = k0 + row;
                int b2 = k >> 6, r = k & 63;
                const float* src = (r < 32) ? (xq + (size_t)(b2 * 32 + r) * H_)
                                            : (xa + (size_t)(b2 * 32 + (r - 32)) * H_);
                xr4[idx] = *(const f32x4*)(src + d4 * 4);
            }
        }
        __syncthreads();
        int c = tid & 127, rh = tid >> 7;
        float acc[8];
#pragma unroll
        for (int i = 0; i < 8; ++i) acc[i] = 0.0f;
        const f32x4* w4 = (const f32x4*)(W + (size_t)c * H_);
        for (int d4 = 0; d4 < 32; ++d4) {
            f32x4 wv = w4[d4];
#pragma unroll
            for (int i = 0; i < 8; ++i) {
                f32x4 x = xr4[(rh * 8 + i) * 32 + d4];
                acc[i] += wv[0]*x[0] + wv[1]*x[1] + wv[2]*x[2] + wv[3]*x[3];
            }
        }
        float bc = bias[c];
        float* res = sbuf + 2048;
#pragma unroll
        for (int i = 0; i < 8; ++i)
            res[(rh * 8 + i) * H_ + c] = fmaxf(acc[i] + bc, 0.0f);
        __syncthreads();
        int ks = tid >> 6, l = tid & 63, n16 = l & 15, g = l >> 4;
        uint16_t hbuf[8];
#pragma unroll
        for (int j = 0; j < 8; ++j)
            hbuf[j] = f2h(res[n16 * H_ + ks * 32 + g * 8 + j]);
        uint8_t* dst;
        if (isx) dst = X2 + (((size_t)b * 4 + ks) << 10) + l * 16;
        else     dst = Y2 + (((size_t)kb * 4 + ks) << 10) + l * 16;
        *(uint64_t*)dst       = ((const uint64_t*)hbuf)[0];
        *(uint64_t*)(dst + 8) = ((const uint64_t*)hbuf)[1];
    } else if (b < 1184) {
        int kt = b - 1152;
        f32x4* ld4 = (f32x4*)sbuf;
#pragma unroll
        for (int i = 0; i < 8; ++i) {
            int idx = tid + i * 256;
            int row = idx >> 5, d4 = idx & 31;
            const float* src = (row < 32) ? (xq + (size_t)(kt * 32 + row) * H_)
                                          : (xa + (size_t)(kt * 32 + row - 32) * H_);
            ld4[idx] = *(const f32x4*)(src + d4 * 4);
        }
        __syncthreads();
#pragma unroll
        for (int i = 0; i < 4; ++i) {
            int id = tid + i * 256;
            int cT = id >> 7, ks = (id >> 6) & 1, l = id & 63;
            int n16 = l & 15, g = l >> 4;
            uint16_t hbuf[8];
#pragma unroll
            for (int j = 0; j < 8; ++j)
                hbuf[j] = f2h(sbuf[(ks * 32 + g * 8 + j) * H_ + cT * 16 + n16]);
            uint8_t* dst = V2 + (((size_t)kt * 16 + cT * 2 + ks) << 10) + l * 16;
            *(uint64_t*)dst       = ((const uint64_t*)hbuf)[0];
            *(uint64_t*)(dst + 8) = ((const uint64_t*)hbuf)[1];
        }
    } else {
        int* flags = (int*)sbuf;
        if (tid == 0) { flags[0] = 0; flags[1] = 0; }
        __syncthreads();
        uint32_t v = ((const uint32_t*)qm)[tid] | ((const uint32_t*)am)[tid];
        if (v & 0xFFu)        atomicOr(&flags[0], 1);
        if (v & 0xFFFFFF00u)  atomicOr(&flags[1], 1);
        __syncthreads();
        int f0 = flags[0], f1 = flags[1];
        int mode = (f0 && !f1) ? 0 : ((!f0 && f1) ? 1 : 2);
        for (int k = tid; k < NK_; k += 256) {
            int b2 = k >> 6, r = k & 63;
            int idx = b2 * 32 + (r < 32 ? r : r - 32);
            const uint8_t* src = (r < 32) ? qm : am;
            int p;
            if (mode == 0)      p = (((const int*)src)[idx] != 0);
            else if (mode == 1) p = (((const float*)src)[idx] != 0.0f);
            else                p = (src[idx] != 0);
            badd[k] = p ? NEGV : 0.0f;
        }
    }
}

// ---------------------------------------------------------------------------
// Flash attention: per-wave-independent k-tiles, batch-issued tile loads.
// Per tile: issue 16 y + 8 vA loads -> S MFMAs -> issue 8 vB loads ->
// softmax (covers vB latency) -> PV. One amortized vmem stall per tile.
// ---------------------------------------------------------------------------
__global__ __launch_bounds__(256, 2) void attn_kernel(
        const uint8_t* __restrict__ X2,
        const uint8_t* __restrict__ Y2,
        const uint8_t* __restrict__ V2,
        const float*   __restrict__ badd,
        const float*   __restrict__ rw,
        float* __restrict__ out) {
    int bid = blockIdx.x;
    int t  = (bid < 256) ? (31 - (bid >> 4)) : ((bid - 256) >> 4);
    int l0 = (bid & 15) << 5;
    int tid = threadIdx.x;

    __shared__ __align__(16) float smem[4 * 64 * 64];   // 64 KB: P (16 KB) then Obuf
    __shared__ float stats_m[4][32];
    __shared__ float stats_l[4][32];

    if (t == 0) {                  // zero_first
        f32x4 z = {0.f, 0.f, 0.f, 0.f};
        f32x4* o4 = (f32x4*)(out + (size_t)l0 * H_);
        for (int i = tid; i < 32 * H_ / 4; i += 256) o4[i] = z;
        return;
    }

    int w = tid >> 6, lane = tid & 63, n16 = lane & 15, g = lane >> 4;
    int prow0 = n16, prow1 = 16 + n16;
    int swz = (n16 & 7) << 4;

    // x fragments: 8 coalesced loads, live whole kernel
    f16x8 xf[2][4];
    {
        const uint8_t* xbase = X2 + (((size_t)(t * 16 + (l0 >> 5)) * 8) << 10) + lane * 16;
#pragma unroll
        for (int rT = 0; rT < 2; ++rT)
#pragma unroll
            for (int ks = 0; ks < 4; ++ks)
                xf[rT][ks] = *(const f16x8*)(xbase + ((rT * 4 + ks) << 10));
    }

    f32x4 zero4 = {0.f, 0.f, 0.f, 0.f};
    f32x4 acc[2][8];
#pragma unroll
    for (int a = 0; a < 2; ++a)
#pragma unroll
        for (int c = 0; c < 8; ++c) acc[a][c] = zero4;

    float m_r[2] = {-INFINITY, -INFINITY};
    float l_r[2] = {0.0f, 0.0f};
    float rww = rw[0];

    char* Pw = (char*)smem + w * 4096;     // per-wave 4 KB P buffer

    for (int kt = w; kt < t; kt += 4) {
        const uint8_t* ybase = Y2 + ((size_t)kt << 14) + lane * 16;
        const uint8_t* vbase = V2 + ((size_t)kt << 14) + lane * 16;

        // ---- issue ALL 16 y loads
        f16x8 yf[4][4];
#pragma unroll
        for (int kkT = 0; kkT < 4; ++kkT)
#pragma unroll
            for (int ks = 0; ks < 4; ++ks)
                yf[kkT][ks] = *(const f16x8*)(ybase + ((kkT * 4 + ks) << 10));

        // ---- issue first-half v loads (cT 0..3)
        f16x8 vbA[4][2];
#pragma unroll
        for (int cT = 0; cT < 4; ++cT) {
            vbA[cT][0] = *(const f16x8*)(vbase + ((cT * 2) << 10));
            vbA[cT][1] = *(const f16x8*)(vbase + ((cT * 2 + 1) << 10));
        }

        // ---- badd for this tile
        f32x4 ba4[4];
#pragma unroll
        for (int kkT = 0; kkT < 4; ++kkT)
            ba4[kkT] = *(const f32x4*)(badd + kt * 64 + kkT * 16 + g * 4);

        // ---- S^T: 32 MFMAs (one amortized wait on y)
        f32x4 ss[4][2];
#pragma unroll
        for (int kkT = 0; kkT < 4; ++kkT) { ss[kkT][0] = zero4; ss[kkT][1] = zero4; }
#pragma unroll
        for (int ks = 0; ks < 4; ++ks)
#pragma unroll
            for (int kkT = 0; kkT < 4; ++kkT) {
                ss[kkT][0] = __builtin_amdgcn_mfma_f32_16x16x32_f16(yf[kkT][ks], xf[0][ks], ss[kkT][0], 0, 0, 0);
                ss[kkT][1] = __builtin_amdgcn_mfma_f32_16x16x32_f16(yf[kkT][ks], xf[1][ks], ss[kkT][1], 0, 0, 0);
            }

        // ---- issue second-half v loads (cT 4..7); softmax below covers latency
        f16x8 vbB[4][2];
#pragma unroll
        for (int cT = 0; cT < 4; ++cT) {
            vbB[cT][0] = *(const f16x8*)(vbase + (((cT + 4) * 2) << 10));
            vbB[cT][1] = *(const f16x8*)(vbase + (((cT + 4) * 2 + 1) << 10));
        }

        // ---- mask + recency bias
        float biasK = rww * (float)(t - kt);
#pragma unroll
        for (int kkT = 0; kkT < 4; ++kkT) {
            f32x4 ba = ba4[kkT] + biasK;
            ss[kkT][0] += ba;
            ss[kkT][1] += ba;
        }

        // ---- per-row online max
        float sc[2];
#pragma unroll
        for (int rT = 0; rT < 2; ++rT) {
            f32x4 mx4 = ss[0][rT];
#pragma unroll
            for (int kkT = 1; kkT < 4; ++kkT) {
                mx4[0] = fmaxf(mx4[0], ss[kkT][rT][0]);
                mx4[1] = fmaxf(mx4[1], ss[kkT][rT][1]);
                mx4[2] = fmaxf(mx4[2], ss[kkT][rT][2]);
                mx4[3] = fmaxf(mx4[3], ss[kkT][rT][3]);
            }
            float mx = fmaxf(fmaxf(mx4[0], mx4[1]), fmaxf(mx4[2], mx4[3]));
            mx = fmaxf(mx, __shfl_xor(mx, 16));
            mx = fmaxf(mx, __shfl_xor(mx, 32));
            float mn = fmaxf(m_r[rT], mx);
            sc[rT] = __expf(m_r[rT] - mn);
            m_r[rT] = mn;
        }

        // ---- P = exp(s - m), partial sums, write P to wave-local LDS
#pragma unroll
        for (int rT = 0; rT < 2; ++rT) {
            int r = rT ? prow1 : prow0;
            float mn = m_r[rT];
            float ps = 0.0f;
#pragma unroll
            for (int kkT = 0; kkT < 4; ++kkT) {
                f32x4 p;
#pragma unroll
                for (int q = 0; q < 4; ++q) p[q] = __expf(ss[kkT][rT][q] - mn);
                ps += (p[0] + p[1]) + (p[2] + p[3]);
                union { h16x2 h2[2]; uint64_t u64; } pk;
                pk.h2[0] = __builtin_amdgcn_cvt_pkrtz(p[0], p[1]);
                pk.h2[1] = __builtin_amdgcn_cvt_pkrtz(p[2], p[3]);
                *(uint64_t*)(Pw + r * 128 + ((kkT * 32 + g * 8) ^ swz)) = pk.u64;
            }
            ps += __shfl_xor(ps, 16);
            ps += __shfl_xor(ps, 32);
            l_r[rT] = l_r[rT] * sc[rT] + ps;
        }

        asm volatile("s_waitcnt lgkmcnt(0)" ::: "memory");

        // ---- rescale O accumulator (skip when max didn't move)
        if (!__all((sc[0] == 1.0f) && (sc[1] == 1.0f))) {
#pragma unroll
            for (int rT = 0; rT < 2; ++rT) {
                f32x4 s4;
#pragma unroll
                for (int q = 0; q < 4; ++q) s4[q] = __shfl(sc[rT], (g << 2) + q);
#pragma unroll
                for (int cT = 0; cT < 8; ++cT) acc[rT][cT] *= s4;
            }
        }

        // ---- PV: P A-frags from LDS, v regs long since landed, 32 MFMAs
        f16x8 pa[2][2];
#pragma unroll
        for (int rT = 0; rT < 2; ++rT) {
            int r = rT ? prow1 : prow0;
#pragma unroll
            for (int ks = 0; ks < 2; ++ks)
                pa[rT][ks] = *(const f16x8*)(Pw + r * 128 + ((ks * 64 + g * 16) ^ swz));
        }
#pragma unroll
        for (int cT = 0; cT < 4; ++cT)
#pragma unroll
            for (int rT = 0; rT < 2; ++rT) {
                acc[rT][cT] = __builtin_amdgcn_mfma_f32_16x16x32_f16(pa[rT][0], vbA[cT][0], acc[rT][cT], 0, 0, 0);
                acc[rT][cT] = __builtin_amdgcn_mfma_f32_16x16x32_f16(pa[rT][1], vbA[cT][1], acc[rT][cT], 0, 0, 0);
            }
#pragma unroll
        for (int cT = 0; cT < 4; ++cT)
#pragma unroll
            for (int rT = 0; rT < 2; ++rT) {
                acc[rT][cT + 4] = __builtin_amdgcn_mfma_f32_16x16x32_f16(pa[rT][0], vbB[cT][0], acc[rT][cT + 4], 0, 0, 0);
                acc[rT][cT + 4] = __builtin_amdgcn_mfma_f32_16x16x32_f16(pa[rT][1], vbB[cT][1], acc[rT][cT + 4], 0, 0, 0);
            }
    }

    // ---- cross-wave combine
    if (g == 0) {
        stats_m[w][n16]      = m_r[0];
        stats_m[w][16 + n16] = m_r[1];
        stats_l[w][n16]      = l_r[0];
        stats_l[w][16 + n16] = l_r[1];
    }
    __syncthreads();

    float fac[2][4];
#pragma unroll
    for (int rT = 0; rT < 2; ++rT)
#pragma unroll
        for (int q = 0; q < 4; ++q) {
            int r = rT * 16 + (g << 2) + q;
            float m0 = stats_m[0][r], m1 = stats_m[1][r];
            float m2 = stats_m[2][r], m3 = stats_m[3][r];
            float mf = fmaxf(fmaxf(m0, m1), fmaxf(m2, m3));
            float lf = stats_l[0][r] * __expf(m0 - mf) + stats_l[1][r] * __expf(m1 - mf)
                     + stats_l[2][r] * __expf(m2 - mf) + stats_l[3][r] * __expf(m3 - mf);
            float mw = stats_m[w][r];
            fac[rT][q] = __expf(mw - mf) / lf;
        }

    float* Ob = smem + w * 4096;
#pragma unroll
    for (int rT = 0; rT < 2; ++rT)
#pragma unroll
        for (int cT = 0; cT < 8; ++cT)
#pragma unroll
            for (int q = 0; q < 4; ++q)
                Ob[((rT * 8 + cT) * 4 + q) * 64 + lane] = acc[rT][cT][q] * fac[rT][q];
    __syncthreads();

    size_t obase = (size_t)(t * L1_ + l0) * H_;
#pragma unroll
    for (int s = 0; s < 16; ++s) {
        int slot = w * 16 + s;
        float v = smem[slot * 64 + lane] + smem[4096 + slot * 64 + lane]
                + smem[8192 + slot * 64 + lane] + smem[12288 + slot * 64 + lane];
        int rT = slot >> 5, cT = (slot >> 2) & 7, q = slot & 3;
        out[obase + (size_t)(rT * 16 + (g << 2) + q) * H_ + cT * 16 + n16] = v;
    }
}

// ---------------------------------------------------------------------------
extern "C" void kernel_launch(void* const* d_in, const int* in_sizes, int n_in,
                              void* d_out, int out_size, void* d_ws, size_t ws_size,
                              hipStream_t stream) {
    const float*   xd   = (const float*)d_in[0];
    const float*   xq   = (const float*)d_in[1];
    const float*   xa   = (const float*)d_in[2];
    const float*   W    = (const float*)d_in[3];
    const float*   bias = (const float*)d_in[4];
    const float*   rw   = (const float*)d_in[5];
    const uint8_t* qm   = (const uint8_t*)d_in[6];
    const uint8_t* am   = (const uint8_t*)d_in[7];
    float* out = (float*)d_out;

    char* ws = (char*)d_ws;
    float*   badd = (float*)ws;                          // 8 KB
    uint8_t* Y2   = (uint8_t*)(ws + 8192);               // 512 KB
    uint8_t* V2   = (uint8_t*)(ws + 8192 + 524288);      // 512 KB
    uint8_t* X2   = (uint8_t*)(ws + 8192 + 2 * 524288);  // 4 MB

    preproc_kernel<<<1185, 256, 0, stream>>>(xd, xq, xa, W, bias, qm, am,
                                             X2, Y2, V2, badd);
    attn_kernel<<<512, 256, 0, stream>>>(X2, Y2, V2, badd, rw, out);
}

// Round 8
// 37.135 us; speedup vs baseline: 116.1159x; 1.3393x over previous
//
#include <hip/hip_runtime.h>
#include <stdint.h>

#define NEGV (-1e30f)

constexpr int L1_ = 512;
constexpr int H_  = 128;
constexpr int NK_ = 2048;   // 32 turns * 64 tokens

typedef __attribute__((ext_vector_type(8))) _Float16 f16x8;
typedef __attribute__((ext_vector_type(2))) __fp16   h16x2;
typedef __attribute__((ext_vector_type(4))) float    f32x4;

static __device__ __forceinline__ uint16_t f2h(float x) {
    union { _Float16 h; uint16_t u; } cv; cv.h = (_Float16)x; return cv.u;
}

// Fragment-major layouts (16B chunk per lane, lane = (g<<4)|n16):
//  Y2[kt(32)][kkT(4)][ks(4)][lane]  chunk = yp[kt*64+kkT*16+n16][ks*32+g*8 .. +8]
//  V2[kt(32)][cT(8)][ks(2)][lane]   chunk = dlg[kt*64+ks*32+g*8+j][cT*16+n16]
//  W2[cT(8)][ks(4)][lane]           chunk = W [cT*16+n16][ks*32+g*8 .. +8]
// x-projection is computed inside attn_kernel via MFMA + W2 (no X2 tensor).

// ---------------------------------------------------------------------------
// Preprocessing, 256 threads/block:
//  [0,128):   yproj 16 rows -> Y2      (f32 VALU, then fragment-pack)
//  [128,160): dlg turn -> V2           (LDS transpose)
//  160:       masks -> badd f32[2048] in {0,-1e30}
//  161:       W -> W2 fragment pack (fp16)
// ---------------------------------------------------------------------------
__global__ __launch_bounds__(256) void preproc_kernel(
        const float* __restrict__ xq,
        const float* __restrict__ xa,
        const float* __restrict__ W,
        const float* __restrict__ bias,
        const uint8_t* __restrict__ qm,
        const uint8_t* __restrict__ am,
        uint8_t* __restrict__ Y2,
        uint8_t* __restrict__ V2,
        uint8_t* __restrict__ W2,
        float* __restrict__ badd) {
    int b = blockIdx.x;
    int tid = threadIdx.x;
    __shared__ __align__(16) float sbuf[64 * 128];   // 32 KB

    if (b < 128) {
        // ---- yproj: rows [b*16, b*16+16) of dlg -> relu(@W.T+b) -> Y2 frags
        int k0 = b * 16;
        f32x4* xr4 = (f32x4*)sbuf;
#pragma unroll
        for (int i = 0; i < 2; ++i) {
            int idx = tid + i * 256;           // 512 f32x4
            int row = idx >> 5, d4 = idx & 31;
            int k = k0 + row;
            int b2 = k >> 6, r = k & 63;
            const float* src = (r < 32) ? (xq + (size_t)(b2 * 32 + r) * H_)
                                        : (xa + (size_t)(b2 * 32 + (r - 32)) * H_);
            xr4[idx] = *(const f32x4*)(src + d4 * 4);
        }
        __syncthreads();
        int c = tid & 127, rh = tid >> 7;
        float acc[8];
#pragma unroll
        for (int i = 0; i < 8; ++i) acc[i] = 0.0f;
        const f32x4* w4 = (const f32x4*)(W + (size_t)c * H_);
        for (int d4 = 0; d4 < 32; ++d4) {
            f32x4 wv = w4[d4];
#pragma unroll
            for (int i = 0; i < 8; ++i) {
                f32x4 x = xr4[(rh * 8 + i) * 32 + d4];
                acc[i] += wv[0]*x[0] + wv[1]*x[1] + wv[2]*x[2] + wv[3]*x[3];
            }
        }
        float bc = bias[c];
        float* res = sbuf + 2048;
#pragma unroll
        for (int i = 0; i < 8; ++i)
            res[(rh * 8 + i) * H_ + c] = fmaxf(acc[i] + bc, 0.0f);
        __syncthreads();
        int ks = tid >> 6, l = tid & 63, n16 = l & 15, g = l >> 4;
        uint16_t hbuf[8];
#pragma unroll
        for (int j = 0; j < 8; ++j)
            hbuf[j] = f2h(res[n16 * H_ + ks * 32 + g * 8 + j]);
        uint8_t* dst = Y2 + (((size_t)b * 4 + ks) << 10) + l * 16;   // b = kt*4+kkT
        *(uint64_t*)dst       = ((const uint64_t*)hbuf)[0];
        *(uint64_t*)(dst + 8) = ((const uint64_t*)hbuf)[1];
    } else if (b < 160) {
        // ---- V2: turn kt, LDS transpose of 64 dialog rows
        int kt = b - 128;
        f32x4* ld4 = (f32x4*)sbuf;
#pragma unroll
        for (int i = 0; i < 8; ++i) {
            int idx = tid + i * 256;
            int row = idx >> 5, d4 = idx & 31;
            const float* src = (row < 32) ? (xq + (size_t)(kt * 32 + row) * H_)
                                          : (xa + (size_t)(kt * 32 + row - 32) * H_);
            ld4[idx] = *(const f32x4*)(src + d4 * 4);
        }
        __syncthreads();
#pragma unroll
        for (int i = 0; i < 4; ++i) {
            int id = tid + i * 256;
            int cT = id >> 7, ks = (id >> 6) & 1, l = id & 63;
            int n16 = l & 15, g = l >> 4;
            uint16_t hbuf[8];
#pragma unroll
            for (int j = 0; j < 8; ++j)
                hbuf[j] = f2h(sbuf[(ks * 32 + g * 8 + j) * H_ + cT * 16 + n16]);
            uint8_t* dst = V2 + (((size_t)kt * 16 + cT * 2 + ks) << 10) + l * 16;
            *(uint64_t*)dst       = ((const uint64_t*)hbuf)[0];
            *(uint64_t*)(dst + 8) = ((const uint64_t*)hbuf)[1];
        }
    } else if (b == 160) {
        // ---- pad detection + badd
        int* flags = (int*)sbuf;
        if (tid == 0) { flags[0] = 0; flags[1] = 0; }
        __syncthreads();
        uint32_t v = ((const uint32_t*)qm)[tid] | ((const uint32_t*)am)[tid];
        if (v & 0xFFu)        atomicOr(&flags[0], 1);
        if (v & 0xFFFFFF00u)  atomicOr(&flags[1], 1);
        __syncthreads();
        int f0 = flags[0], f1 = flags[1];
        int mode = (f0 && !f1) ? 0 : ((!f0 && f1) ? 1 : 2);
        for (int k = tid; k < NK_; k += 256) {
            int b2 = k >> 6, r = k & 63;
            int idx = b2 * 32 + (r < 32 ? r : r - 32);
            const uint8_t* src = (r < 32) ? qm : am;
            int p;
            if (mode == 0)      p = (((const int*)src)[idx] != 0);
            else if (mode == 1) p = (((const float*)src)[idx] != 0.0f);
            else                p = (src[idx] != 0);
            badd[k] = p ? NEGV : 0.0f;
        }
    } else {
        // ---- W2 pack: two 64-row halves of W through LDS
        for (int h = 0; h < 2; ++h) {
            f32x4* s4 = (f32x4*)sbuf;
#pragma unroll
            for (int i = 0; i < 8; ++i) {
                int idx = tid + i * 256;      // 2048 f32x4
                s4[idx] = *(const f32x4*)(W + (size_t)h * 64 * H_ + idx * 4);
            }
            __syncthreads();
#pragma unroll
            for (int i = 0; i < 4; ++i) {
                int id = tid + i * 256;       // 1024
                int ct = id >> 8, ks = (id >> 6) & 3, l = id & 63;
                int n16 = l & 15, g = l >> 4;
                uint16_t hb[8];
#pragma unroll
                for (int j = 0; j < 8; ++j)
                    hb[j] = f2h(sbuf[(ct * 16 + n16) * H_ + ks * 32 + g * 8 + j]);
                uint8_t* dst = W2 + (((size_t)((h * 4 + ct) * 4 + ks)) << 10) + l * 16;
                *(uint64_t*)dst       = ((const uint64_t*)hb)[0];
                *(uint64_t*)(dst + 8) = ((const uint64_t*)hb)[1];
            }
            __syncthreads();
        }
    }
}

// ---------------------------------------------------------------------------
// Flash attention with fused x-projection (MFMA) and fenced batch loads.
// Pairing: bid<256 -> t in {31..17,16}; bid>=256 -> t in {1..15,0}; CU pair
// sums to 32 k-tiles (t=0 rides with t=16).
// ---------------------------------------------------------------------------
__global__ __launch_bounds__(256, 2) void attn_kernel(
        const float*   __restrict__ xd,
        const uint8_t* __restrict__ W2,
        const float*   __restrict__ bias,
        const uint8_t* __restrict__ Y2,
        const uint8_t* __restrict__ V2,
        const float*   __restrict__ badd,
        const float*   __restrict__ rw,
        float* __restrict__ out) {
    int bid = blockIdx.x;
    int t, lt;
    if (bid < 256) { int p = bid >> 4; t = (p < 15) ? 31 - p : 16; lt = bid & 15; }
    else           { int b2 = bid - 256; int p = b2 >> 4; t = (p < 15) ? p + 1 : 0; lt = b2 & 15; }
    int l0 = lt << 5;
    int tid = threadIdx.x;

    __shared__ __align__(16) float smem[4 * 64 * 64];   // 64 KB
    __shared__ float stats_m[4][32];
    __shared__ float stats_l[4][32];

    if (t == 0) {                  // zero_first: batch-0 rows are 0
        f32x4 z = {0.f, 0.f, 0.f, 0.f};
        f32x4* o4 = (f32x4*)(out + (size_t)l0 * H_);
        for (int i = tid; i < 32 * H_ / 4; i += 256) o4[i] = z;
        return;
    }

    int w = tid >> 6, lane = tid & 63, n16 = lane & 15, g = lane >> 4;
    int prow0 = n16, prow1 = 16 + n16;
    int swzP = (n16 & 7) << 4;

    // ================= x-projection prologue (MFMA) =================
    uint16_t* xbuf  = (uint16_t*)((char*)smem + 16384);   // [32][128] fp16 swz
    uint16_t* xpbuf = (uint16_t*)((char*)smem + 24576);   // [32][128] fp16 swz
    {
        const float* xsrc = xd + (size_t)(t * L1_ + l0) * H_;
#pragma unroll
        for (int i = 0; i < 4; ++i) {
            int idx = tid + i * 256;          // 1024 f32x4
            int row = idx >> 5, c4 = idx & 31;
            f32x4 v = *(const f32x4*)(xsrc + idx * 4);
            uint16_t hb[4] = { f2h(v[0]), f2h(v[1]), f2h(v[2]), f2h(v[3]) };
            *(uint64_t*)((char*)xbuf + row * 256 + ((c4 * 8) ^ ((row & 7) << 4)))
                = *(const uint64_t*)hb;
        }
    }
    __syncthreads();
    {
        f16x8 af[2][4];
#pragma unroll
        for (int rT = 0; rT < 2; ++rT) {
            int row = rT * 16 + n16, swz = (row & 7) << 4;
#pragma unroll
            for (int ks = 0; ks < 4; ++ks)
                af[rT][ks] = *(const f16x8*)((char*)xbuf + row * 256 + ((ks * 64 + g * 16) ^ swz));
        }
        int cTa = 2 * w, cTb = 2 * w + 1;
        f32x4 z4 = {0.f, 0.f, 0.f, 0.f};
        f32x4 d00 = z4, d01 = z4, d10 = z4, d11 = z4;
#pragma unroll
        for (int ks = 0; ks < 4; ++ks) {
            f16x8 wfa = *(const f16x8*)(W2 + (((size_t)cTa * 4 + ks) << 10) + lane * 16);
            f16x8 wfb = *(const f16x8*)(W2 + (((size_t)cTb * 4 + ks) << 10) + lane * 16);
            d00 = __builtin_amdgcn_mfma_f32_16x16x32_f16(af[0][ks], wfa, d00, 0, 0, 0);
            d10 = __builtin_amdgcn_mfma_f32_16x16x32_f16(af[1][ks], wfa, d10, 0, 0, 0);
            d01 = __builtin_amdgcn_mfma_f32_16x16x32_f16(af[0][ks], wfb, d01, 0, 0, 0);
            d11 = __builtin_amdgcn_mfma_f32_16x16x32_f16(af[1][ks], wfb, d11, 0, 0, 0);
        }
        float bba = bias[cTa * 16 + n16], bbb = bias[cTb * 16 + n16];
#pragma unroll
        for (int rT = 0; rT < 2; ++rT) {
            const f32x4& da = rT ? d10 : d00;
            const f32x4& db = rT ? d11 : d01;
#pragma unroll
            for (int q = 0; q < 4; ++q) {
                int row = rT * 16 + g * 4 + q, swz = (row & 7) << 4;
                *(uint16_t*)((char*)xpbuf + row * 256 + (((cTa * 16 + n16) * 2) ^ swz))
                    = f2h(fmaxf(da[q] + bba, 0.0f));
                *(uint16_t*)((char*)xpbuf + row * 256 + (((cTb * 16 + n16) * 2) ^ swz))
                    = f2h(fmaxf(db[q] + bbb, 0.0f));
            }
        }
    }
    __syncthreads();
    f16x8 xf[2][4];
#pragma unroll
    for (int rT = 0; rT < 2; ++rT) {
        int row = rT * 16 + n16, swz = (row & 7) << 4;
#pragma unroll
        for (int ks = 0; ks < 4; ++ks)
            xf[rT][ks] = *(const f16x8*)((char*)xpbuf + row * 256 + ((ks * 64 + g * 16) ^ swz));
    }

    // ================= main loop =================
    f32x4 zero4 = {0.f, 0.f, 0.f, 0.f};
    f32x4 acc[2][8];
#pragma unroll
    for (int a = 0; a < 2; ++a)
#pragma unroll
        for (int c = 0; c < 8; ++c) acc[a][c] = zero4;

    float m_r[2] = {-INFINITY, -INFINITY};
    float l_r[2] = {0.0f, 0.0f};
    float rww = rw[0];

    char* Pw = (char*)smem + w * 4096;     // per-wave 4 KB P buffer

    for (int kt = w; kt < t; kt += 4) {
        const uint8_t* ybase = Y2 + ((size_t)kt << 14) + lane * 16;
        const uint8_t* vbase = V2 + ((size_t)kt << 14) + lane * 16;

        // ---- batch-issue: 16 y + 8 vA + 4 badd loads, then FENCE
        f16x8 yf[4][4];
#pragma unroll
        for (int kkT = 0; kkT < 4; ++kkT)
#pragma unroll
            for (int ks = 0; ks < 4; ++ks)
                yf[kkT][ks] = *(const f16x8*)(ybase + ((kkT * 4 + ks) << 10));
        f16x8 vbA[4][2];
#pragma unroll
        for (int cT = 0; cT < 4; ++cT) {
            vbA[cT][0] = *(const f16x8*)(vbase + ((cT * 2) << 10));
            vbA[cT][1] = *(const f16x8*)(vbase + ((cT * 2 + 1) << 10));
        }
        f32x4 ba4[4];
#pragma unroll
        for (int kkT = 0; kkT < 4; ++kkT)
            ba4[kkT] = *(const f32x4*)(badd + kt * 64 + kkT * 16 + g * 4);
        __builtin_amdgcn_sched_barrier(0);

        // ---- S^T: 32 MFMAs
        f32x4 ss[4][2];
#pragma unroll
        for (int kkT = 0; kkT < 4; ++kkT) { ss[kkT][0] = zero4; ss[kkT][1] = zero4; }
#pragma unroll
        for (int ks = 0; ks < 4; ++ks)
#pragma unroll
            for (int kkT = 0; kkT < 4; ++kkT) {
                ss[kkT][0] = __builtin_amdgcn_mfma_f32_16x16x32_f16(yf[kkT][ks], xf[0][ks], ss[kkT][0], 0, 0, 0);
                ss[kkT][1] = __builtin_amdgcn_mfma_f32_16x16x32_f16(yf[kkT][ks], xf[1][ks], ss[kkT][1], 0, 0, 0);
            }

        // ---- batch-issue second-half v loads, FENCE (land under softmax)
        f16x8 vbB[4][2];
#pragma unroll
        for (int cT = 0; cT < 4; ++cT) {
            vbB[cT][0] = *(const f16x8*)(vbase + (((cT + 4) * 2) << 10));
            vbB[cT][1] = *(const f16x8*)(vbase + (((cT + 4) * 2 + 1) << 10));
        }
        __builtin_amdgcn_sched_barrier(0);

        // ---- mask + recency bias
        float biasK = rww * (float)(t - kt);
#pragma unroll
        for (int kkT = 0; kkT < 4; ++kkT) {
            f32x4 ba = ba4[kkT] + biasK;
            ss[kkT][0] += ba;
            ss[kkT][1] += ba;
        }

        // ---- per-row online max
        float sc[2];
#pragma unroll
        for (int rT = 0; rT < 2; ++rT) {
            f32x4 mx4 = ss[0][rT];
#pragma unroll
            for (int kkT = 1; kkT < 4; ++kkT) {
                mx4[0] = fmaxf(mx4[0], ss[kkT][rT][0]);
                mx4[1] = fmaxf(mx4[1], ss[kkT][rT][1]);
                mx4[2] = fmaxf(mx4[2], ss[kkT][rT][2]);
                mx4[3] = fmaxf(mx4[3], ss[kkT][rT][3]);
            }
            float mx = fmaxf(fmaxf(mx4[0], mx4[1]), fmaxf(mx4[2], mx4[3]));
            mx = fmaxf(mx, __shfl_xor(mx, 16));
            mx = fmaxf(mx, __shfl_xor(mx, 32));
            float mn = fmaxf(m_r[rT], mx);
            sc[rT] = __expf(m_r[rT] - mn);
            m_r[rT] = mn;
        }

        // ---- P = exp(s - m), partial sums, write P to wave-local LDS
#pragma unroll
        for (int rT = 0; rT < 2; ++rT) {
            int r = rT ? prow1 : prow0;
            float mn = m_r[rT];
            float ps = 0.0f;
#pragma unroll
            for (int kkT = 0; kkT < 4; ++kkT) {
                f32x4 p;
#pragma unroll
                for (int q = 0; q < 4; ++q) p[q] = __expf(ss[kkT][rT][q] - mn);
                ps += (p[0] + p[1]) + (p[2] + p[3]);
                union { h16x2 h2[2]; uint64_t u64; } pk;
                pk.h2[0] = __builtin_amdgcn_cvt_pkrtz(p[0], p[1]);
                pk.h2[1] = __builtin_amdgcn_cvt_pkrtz(p[2], p[3]);
                *(uint64_t*)(Pw + r * 128 + ((kkT * 32 + g * 8) ^ swzP)) = pk.u64;
            }
            ps += __shfl_xor(ps, 16);
            ps += __shfl_xor(ps, 32);
            l_r[rT] = l_r[rT] * sc[rT] + ps;
        }

        asm volatile("s_waitcnt lgkmcnt(0)" ::: "memory");

        // ---- rescale O accumulator (skip when max didn't move)
        if (!__all((sc[0] == 1.0f) && (sc[1] == 1.0f))) {
#pragma unroll
            for (int rT = 0; rT < 2; ++rT) {
                f32x4 s4;
#pragma unroll
                for (int q = 0; q < 4; ++q) s4[q] = __shfl(sc[rT], (g << 2) + q);
#pragma unroll
                for (int cT = 0; cT < 8; ++cT) acc[rT][cT] *= s4;
            }
        }

        // ---- PV: 32 MFMAs
        f16x8 pa[2][2];
#pragma unroll
        for (int rT = 0; rT < 2; ++rT) {
            int r = rT ? prow1 : prow0;
#pragma unroll
            for (int ks = 0; ks < 2; ++ks)
                pa[rT][ks] = *(const f16x8*)(Pw + r * 128 + ((ks * 64 + g * 16) ^ swzP));
        }
#pragma unroll
        for (int cT = 0; cT < 4; ++cT)
#pragma unroll
            for (int rT = 0; rT < 2; ++rT) {
                acc[rT][cT] = __builtin_amdgcn_mfma_f32_16x16x32_f16(pa[rT][0], vbA[cT][0], acc[rT][cT], 0, 0, 0);
                acc[rT][cT] = __builtin_amdgcn_mfma_f32_16x16x32_f16(pa[rT][1], vbA[cT][1], acc[rT][cT], 0, 0, 0);
            }
#pragma unroll
        for (int cT = 0; cT < 4; ++cT)
#pragma unroll
            for (int rT = 0; rT < 2; ++rT) {
                acc[rT][cT + 4] = __builtin_amdgcn_mfma_f32_16x16x32_f16(pa[rT][0], vbB[cT][0], acc[rT][cT + 4], 0, 0, 0);
                acc[rT][cT + 4] = __builtin_amdgcn_mfma_f32_16x16x32_f16(pa[rT][1], vbB[cT][1], acc[rT][cT + 4], 0, 0, 0);
            }
    }

    // ---- cross-wave combine
    if (g == 0) {
        stats_m[w][n16]      = m_r[0];
        stats_m[w][16 + n16] = m_r[1];
        stats_l[w][n16]      = l_r[0];
        stats_l[w][16 + n16] = l_r[1];
    }
    __syncthreads();

    float fac[2][4];
#pragma unroll
    for (int rT = 0; rT < 2; ++rT)
#pragma unroll
        for (int q = 0; q < 4; ++q) {
            int r = rT * 16 + (g << 2) + q;
            float m0 = stats_m[0][r], m1 = stats_m[1][r];
            float m2 = stats_m[2][r], m3 = stats_m[3][r];
            float mf = fmaxf(fmaxf(m0, m1), fmaxf(m2, m3));
            float lf = stats_l[0][r] * __expf(m0 - mf) + stats_l[1][r] * __expf(m1 - mf)
                     + stats_l[2][r] * __expf(m2 - mf) + stats_l[3][r] * __expf(m3 - mf);
            float mw = stats_m[w][r];
            fac[rT][q] = __expf(mw - mf) / lf;
        }

    float* Ob = smem + w * 4096;
#pragma unroll
    for (int rT = 0; rT < 2; ++rT)
#pragma unroll
        for (int cT = 0; cT < 8; ++cT)
#pragma unroll
            for (int q = 0; q < 4; ++q)
                Ob[((rT * 8 + cT) * 4 + q) * 64 + lane] = acc[rT][cT][q] * fac[rT][q];
    __syncthreads();

    size_t obase = (size_t)(t * L1_ + l0) * H_;
#pragma unroll
    for (int s = 0; s < 16; ++s) {
        int slot = w * 16 + s;
        float v = smem[slot * 64 + lane] + smem[4096 + slot * 64 + lane]
                + smem[8192 + slot * 64 + lane] + smem[12288 + slot * 64 + lane];
        int rT = slot >> 5, cT = (slot >> 2) & 7, q = slot & 3;
        out[obase + (size_t)(rT * 16 + (g << 2) + q) * H_ + cT * 16 + n16] = v;
    }
}

// ---------------------------------------------------------------------------
extern "C" void kernel_launch(void* const* d_in, const int* in_sizes, int n_in,
                              void* d_out, int out_size, void* d_ws, size_t ws_size,
                              hipStream_t stream) {
    const float*   xd   = (const float*)d_in[0];
    const float*   xq   = (const float*)d_in[1];
    const float*   xa   = (const float*)d_in[2];
    const float*   W    = (const float*)d_in[3];
    const float*   bias = (const float*)d_in[4];
    const float*   rw   = (const float*)d_in[5];
    const uint8_t* qm   = (const uint8_t*)d_in[6];
    const uint8_t* am   = (const uint8_t*)d_in[7];
    float* out = (float*)d_out;

    char* ws = (char*)d_ws;
    float*   badd = (float*)ws;                          // 8 KB
    uint8_t* Y2   = (uint8_t*)(ws + 8192);               // 512 KB
    uint8_t* V2   = (uint8_t*)(ws + 8192 + 524288);      // 512 KB
    uint8_t* W2   = (uint8_t*)(ws + 8192 + 2 * 524288);  // 32 KB

    preproc_kernel<<<162, 256, 0, stream>>>(xq, xa, W, bias, qm, am,
                                            Y2, V2, W2, badd);
    attn_kernel<<<512, 256, 0, stream>>>(xd, W2, bias, Y2, V2, badd, rw, out);
}